// Round 1
// baseline (2957.199 us; speedup 1.0000x reference)
//
#include <hip/hip_runtime.h>
#include <hip/hip_bf16.h>
#include <math.h>

#define N_NODES 100000
#define N_EDGES 1600000
#define HC 64          // H*C
#define NHEADS 2
#define NLAYERS 4
#define ECLS 5

// ---------------- helpers ----------------
__device__ inline void atomicMaxF(float* addr, float v) {
    // works for mixed signs with init = -inf
    if (v >= 0.f) atomicMax((int*)addr, __float_as_int(v));
    else          atomicMin((unsigned int*)addr, __float_as_uint(v));
}

// ---------------- kernels ----------------

// Precompute escore[l][c][h] = dot(eemb[l][c][h*32..], att_src[l][h][..])
__global__ void k_escore(const float* __restrict__ eemb,
                         const float* __restrict__ att_src,
                         float* __restrict__ escore) {
    int idx = threadIdx.x;
    if (idx < NLAYERS * ECLS * NHEADS) {
        int l = idx / (ECLS * NHEADS);
        int r = idx % (ECLS * NHEADS);
        int c = r >> 1;
        int h = r & 1;
        float s = 0.f;
        const float* ev = eemb + l * ECLS * HC + c * HC + h * 32;
        const float* av = att_src + l * HC + h * 32;
        for (int k = 0; k < 32; ++k) s += ev[k] * av[k];
        escore[idx] = s;
    }
}

// Per-node: hcur = in @ W ; s_src/s_dst attention partials; init accumulators.
// Block = 256 threads = 4 nodes x 64 channels (one wave per node).
__global__ void k_linear(const float* __restrict__ in, int Fin,
                         const float* __restrict__ W,        // [Fin][64]
                         const float* __restrict__ asrc,     // [2][32]
                         const float* __restrict__ adst,     // [2][32]
                         float* __restrict__ hcur,
                         float* __restrict__ ssrc, float* __restrict__ sdst,
                         float* __restrict__ outacc,
                         float* __restrict__ amax, float* __restrict__ denom) {
    __shared__ float Wl[64 * 64];
    int tid = threadIdx.x;
    for (int i = tid; i < Fin * HC; i += 256) Wl[i] = W[i];
    __syncthreads();

    int n = blockIdx.x * 4 + (tid >> 6);
    int j = tid & 63;
    if (n >= N_NODES) return;

    const float* row = in + (size_t)n * Fin;
    float acc = 0.f;
    for (int k = 0; k < Fin; ++k) acc += row[k] * Wl[k * HC + j];
    hcur[(size_t)n * HC + j] = acc;

    int head = j >> 5;
    int c = j & 31;
    float ps = acc * asrc[head * 32 + c];
    float pd = acc * adst[head * 32 + c];
    // reduce within each 32-lane half-wave
    for (int off = 16; off > 0; off >>= 1) {
        ps += __shfl_down(ps, off, 32);
        pd += __shfl_down(pd, off, 32);
    }
    if (c == 0) {
        ssrc[n * 2 + head] = ps;
        sdst[n * 2 + head] = pd;
    }
    outacc[(size_t)n * HC + j] = 0.f;
    if (j < 2) {
        amax[n * 2 + j] = -INFINITY;
        denom[n * 2 + j] = 0.f;
    }
}

// Per-edge logits + atomic segment max.
__global__ void k_logits(const int* __restrict__ src, const int* __restrict__ dst,
                         const int* __restrict__ attr,
                         const float* __restrict__ ssrc, const float* __restrict__ sdst,
                         const float* __restrict__ escore_l,   // [5][2]
                         float* __restrict__ logits, float* __restrict__ amax) {
    int e = blockIdx.x * 256 + threadIdx.x;
    if (e >= N_EDGES) return;
    int s = src[e], d = dst[e], a = attr[e];
    float ss0 = ssrc[s * 2 + 0], ss1 = ssrc[s * 2 + 1];
    float sd0 = sdst[d * 2 + 0], sd1 = sdst[d * 2 + 1];
    float x0 = sd0 + ss0 + escore_l[a * 2 + 0];
    float x1 = sd1 + ss1 + escore_l[a * 2 + 1];
    x0 = x0 >= 0.f ? x0 : 0.2f * x0;
    x1 = x1 >= 0.f ? x1 : 0.2f * x1;
    logits[e * 2 + 0] = x0;
    logits[e * 2 + 1] = x1;
    atomicMaxF(&amax[d * 2 + 0], x0);
    atomicMaxF(&amax[d * 2 + 1], x1);
}

// Per-edge exp + atomic segment sum. ex overwrites logits in place.
__global__ void k_exp(const int* __restrict__ dst,
                      float* __restrict__ exlog,
                      const float* __restrict__ amax,
                      float* __restrict__ denom) {
    int e = blockIdx.x * 256 + threadIdx.x;
    if (e >= N_EDGES) return;
    int d = dst[e];
    float x0 = expf(exlog[e * 2 + 0] - amax[d * 2 + 0]);
    float x1 = expf(exlog[e * 2 + 1] - amax[d * 2 + 1]);
    exlog[e * 2 + 0] = x0;
    exlog[e * 2 + 1] = x1;
    atomicAdd(&denom[d * 2 + 0], x0);
    atomicAdd(&denom[d * 2 + 1], x1);
}

// Aggregation: outacc[dst] += alpha * (hcur[src] + eemb[class]).
// Block = 256 threads = 4 edges x 64 channels.
__global__ void k_agg(const int* __restrict__ src, const int* __restrict__ dst,
                      const int* __restrict__ attr,
                      const float* __restrict__ ex, const float* __restrict__ denom,
                      const float* __restrict__ hcur,
                      const float* __restrict__ eemb_l,     // [5][64]
                      float* __restrict__ outacc) {
    int e = blockIdx.x * 4 + (threadIdx.x >> 6);
    int j = threadIdx.x & 63;
    if (e >= N_EDGES) return;
    int s = src[e], d = dst[e], a = attr[e];
    int h = j >> 5;
    float alpha = ex[e * 2 + h] / (denom[d * 2 + h] + 1e-16f);
    float m = hcur[(size_t)s * HC + j] + eemb_l[a * HC + j];
    atomicAdd(&outacc[(size_t)d * HC + j], alpha * m);
}

// Finalize: hnext = elu(outacc + bias)
__global__ void k_fin(const float* __restrict__ outacc, const float* __restrict__ bias_l,
                      float* __restrict__ hnext) {
    int idx = blockIdx.x * 256 + threadIdx.x;
    if (idx >= N_NODES * HC) return;
    float v = outacc[idx] + bias_l[idx & 63];
    hnext[idx] = v > 0.f ? v : expm1f(v);
}

// Decoder: out[k] = dot(h[4k], h[4k+1]) over 64 channels. 4 pairs/block.
__global__ void k_dec(const float* __restrict__ h, float* __restrict__ out) {
    int k = blockIdx.x * 4 + (threadIdx.x >> 6);
    int j = threadIdx.x & 63;
    if (k >= N_NODES / 4) return;
    float u = h[(size_t)(4 * k) * HC + j];
    float v = h[(size_t)(4 * k + 1) * HC + j];
    float p = u * v;
    for (int off = 32; off > 0; off >>= 1) p += __shfl_down(p, off, 64);
    if (j == 0) out[k] = p;
}

// ---------------- launch ----------------
extern "C" void kernel_launch(void* const* d_in, const int* in_sizes, int n_in,
                              void* d_out, int out_size, void* d_ws, size_t ws_size,
                              hipStream_t stream) {
    const float* x       = (const float*)d_in[0];   // [N,4]
    const float* W0      = (const float*)d_in[1];   // [4,64]
    const float* W13     = (const float*)d_in[2];   // [3,64,64]
    const float* eemb    = (const float*)d_in[3];   // [4,5,64]
    const float* att_src = (const float*)d_in[4];   // [4,2,32]
    const float* att_dst = (const float*)d_in[5];   // [4,2,32]
    const float* bias    = (const float*)d_in[6];   // [4,64]
    const int*   eidx    = (const int*)d_in[7];     // [2,E]
    const int*   eattr   = (const int*)d_in[8];     // [E]
    float* out = (float*)d_out;

    const int* src = eidx;
    const int* dst = eidx + N_EDGES;

    // workspace layout (floats)
    float* ws = (float*)d_ws;
    size_t off = 0;
    float* hprev  = ws + off; off += (size_t)N_NODES * HC;
    float* hcur   = ws + off; off += (size_t)N_NODES * HC;
    float* outacc = ws + off; off += (size_t)N_NODES * HC;
    float* ssrc   = ws + off; off += (size_t)N_NODES * 2;
    float* sdst   = ws + off; off += (size_t)N_NODES * 2;
    float* amax   = ws + off; off += (size_t)N_NODES * 2;
    float* denom  = ws + off; off += (size_t)N_NODES * 2;
    float* exlog  = ws + off; off += (size_t)N_EDGES * 2;
    float* escore = ws + off; off += NLAYERS * ECLS * NHEADS;

    k_escore<<<1, 64, 0, stream>>>(eemb, att_src, escore);

    const int nodeBlocks = (N_NODES + 3) / 4;          // 4 nodes / block
    const int edgeBlocks = (N_EDGES + 255) / 256;      // 1 edge / thread
    const int aggBlocks  = (N_EDGES + 3) / 4;          // 4 edges / block
    const int finBlocks  = (N_NODES * HC + 255) / 256;
    const int decBlocks  = (N_NODES / 4 + 3) / 4;

    for (int l = 0; l < NLAYERS; ++l) {
        const float* in  = (l == 0) ? x : hprev;
        int Fin          = (l == 0) ? 4 : HC;
        const float* W   = (l == 0) ? W0 : (W13 + (size_t)(l - 1) * HC * HC);
        const float* asr = att_src + l * HC;
        const float* ads = att_dst + l * HC;
        const float* el  = eemb + (size_t)l * ECLS * HC;
        const float* esl = escore + l * ECLS * NHEADS;
        const float* bl  = bias + l * HC;

        k_linear<<<nodeBlocks, 256, 0, stream>>>(in, Fin, W, asr, ads,
                                                 hcur, ssrc, sdst, outacc, amax, denom);
        k_logits<<<edgeBlocks, 256, 0, stream>>>(src, dst, eattr, ssrc, sdst, esl,
                                                 exlog, amax);
        k_exp<<<edgeBlocks, 256, 0, stream>>>(dst, exlog, amax, denom);
        k_agg<<<aggBlocks, 256, 0, stream>>>(src, dst, eattr, exlog, denom,
                                             hcur, el, outacc);
        k_fin<<<finBlocks, 256, 0, stream>>>(outacc, bl, hprev);
    }

    k_dec<<<decBlocks, 256, 0, stream>>>(hprev, out);
}

// Round 2
// 1191.894 us; speedup vs baseline: 2.4811x; 2.4811x over previous
//
#include <hip/hip_runtime.h>
#include <hip/hip_bf16.h>
#include <math.h>

#define N_NODES 100000
#define N_EDGES 1600000
#define HC 64          // H*C
#define NHEADS 2
#define NLAYERS 4
#define ECLS 5
#define SCAN_BLOCKS ((N_NODES + 255) / 256)   // 391

// ---------------- CSR build ----------------

__global__ void k_hist(const int* __restrict__ dst, int* __restrict__ deg) {
    int e = blockIdx.x * 256 + threadIdx.x;
    if (e < N_EDGES) atomicAdd(&deg[dst[e]], 1);
}

// Per-block inclusive scan; write block sums to part.
__global__ void k_scan1(const int* __restrict__ deg, int* __restrict__ bscan,
                        int* __restrict__ part) {
    __shared__ int tmp[256];
    int i = blockIdx.x * 256 + threadIdx.x;
    int v = (i < N_NODES) ? deg[i] : 0;
    tmp[threadIdx.x] = v;
    __syncthreads();
    for (int off = 1; off < 256; off <<= 1) {
        int t = (threadIdx.x >= off) ? tmp[threadIdx.x - off] : 0;
        __syncthreads();
        tmp[threadIdx.x] += t;
        __syncthreads();
    }
    if (i < N_NODES) bscan[i] = tmp[threadIdx.x];
    if (threadIdx.x == 255) part[blockIdx.x] = tmp[255];
}

// Single-block exclusive scan of block sums (SCAN_BLOCKS <= 512).
__global__ void k_scan2(int* __restrict__ part) {
    __shared__ int tmp[512];
    int tid = threadIdx.x;
    int v = (tid < SCAN_BLOCKS) ? part[tid] : 0;
    tmp[tid] = v;
    __syncthreads();
    for (int off = 1; off < 512; off <<= 1) {
        int t = (tid >= off) ? tmp[tid - off] : 0;
        __syncthreads();
        tmp[tid] += t;
        __syncthreads();
    }
    if (tid < SCAN_BLOCKS) part[tid] = tmp[tid] - v;   // exclusive
}

// rowstart[i] = global exclusive prefix; cursor copy for scatter.
__global__ void k_scan3(const int* __restrict__ deg, const int* __restrict__ bscan,
                        const int* __restrict__ part,
                        int* __restrict__ rowstart, int* __restrict__ cursor) {
    int i = blockIdx.x * 256 + threadIdx.x;
    if (i < N_NODES) {
        int ex = bscan[i] - deg[i] + part[blockIdx.x];
        rowstart[i] = ex;
        cursor[i] = ex;
    }
    if (i == 0) rowstart[N_NODES] = N_EDGES;
}

// Scatter edges into dst-sorted order; pack src (17b) | attr<<20.
__global__ void k_scatter(const int* __restrict__ src, const int* __restrict__ dst,
                          const int* __restrict__ attr,
                          int* __restrict__ cursor, int* __restrict__ packed) {
    int e = blockIdx.x * 256 + threadIdx.x;
    if (e >= N_EDGES) return;
    int d = dst[e];
    int pos = atomicAdd(&cursor[d], 1);
    packed[pos] = src[e] | (attr[e] << 20);
}

// ---------------- per-layer kernels ----------------

// escore[l][c][h] = dot(eemb[l][c][h*32..], att_src[l][h][..])
__global__ void k_escore(const float* __restrict__ eemb,
                         const float* __restrict__ att_src,
                         float* __restrict__ escore) {
    int idx = threadIdx.x;
    if (idx < NLAYERS * ECLS * NHEADS) {
        int l = idx / (ECLS * NHEADS);
        int r = idx % (ECLS * NHEADS);
        int c = r >> 1;
        int h = r & 1;
        float s = 0.f;
        const float* ev = eemb + l * ECLS * HC + c * HC + h * 32;
        const float* av = att_src + l * HC + h * 32;
        for (int k = 0; k < 32; ++k) s += ev[k] * av[k];
        escore[idx] = s;
    }
}

// hcur = in @ W ; per-node attention partials ssrc/sdst.
// Block = 256 threads = 4 nodes x 64 channels (one wave per node).
__global__ void k_linear(const float* __restrict__ in, int Fin,
                         const float* __restrict__ W,        // [Fin][64]
                         const float* __restrict__ asrc,     // [2][32]
                         const float* __restrict__ adst,     // [2][32]
                         float* __restrict__ hcur,
                         float* __restrict__ ssrc, float* __restrict__ sdst) {
    __shared__ float Wl[64 * 64];
    int tid = threadIdx.x;
    for (int i = tid; i < Fin * HC; i += 256) Wl[i] = W[i];
    __syncthreads();

    int n = blockIdx.x * 4 + (tid >> 6);
    int j = tid & 63;
    if (n >= N_NODES) return;

    const float* row = in + (size_t)n * Fin;
    float acc = 0.f;
    for (int k = 0; k < Fin; ++k) acc += row[k] * Wl[k * HC + j];
    hcur[(size_t)n * HC + j] = acc;

    int head = j >> 5;
    int c = j & 31;
    float ps = acc * asrc[head * 32 + c];
    float pd = acc * adst[head * 32 + c];
    for (int off = 16; off > 0; off >>= 1) {
        ps += __shfl_down(ps, off, 32);
        pd += __shfl_down(pd, off, 32);
    }
    if (c == 0) {
        ssrc[n * 2 + head] = ps;
        sdst[n * 2 + head] = pd;
    }
}

// Fused edge pipeline: one wave per dst node, online softmax + aggregation
// over its CSR segment, then bias + ELU. Atomic-free.
__global__ void k_edge(const int* __restrict__ rowstart, const int* __restrict__ packed,
                       const float* __restrict__ ssrc, const float* __restrict__ sdst,
                       const float* __restrict__ escore_l,   // [5][2]
                       const float* __restrict__ hcur,
                       const float* __restrict__ eemb_l,     // [5][64]
                       const float* __restrict__ bias_l,     // [64]
                       float* __restrict__ hnext) {
    int n = blockIdx.x * 4 + (threadIdx.x >> 6);
    int j = threadIdx.x & 63;
    if (n >= N_NODES) return;
    int h = j >> 5;

    int beg = rowstart[n];
    int end = rowstart[n + 1];
    float sd = sdst[n * 2 + h];

    float m = -INFINITY, ssum = 0.f, acc = 0.f;
    for (int i = beg; i < end; ++i) {
        int p = packed[i];
        int s = p & 0xFFFFF;
        int a = p >> 20;
        float lg = sd + ssrc[s * 2 + h] + escore_l[a * 2 + h];
        lg = lg >= 0.f ? lg : 0.2f * lg;
        float mn = fmaxf(m, lg);
        float sc = __expf(m - mn);      // 0 on first iter (m = -inf)
        float w = __expf(lg - mn);
        float msg = hcur[(size_t)s * HC + j] + eemb_l[a * HC + j];
        ssum = ssum * sc + w;
        acc = acc * sc + w * msg;
        m = mn;
    }
    float v = acc / (ssum + 1e-16f) + bias_l[j];
    hnext[(size_t)n * HC + j] = v > 0.f ? v : expm1f(v);
}

// Decoder: out[k] = dot(h[4k], h[4k+1]) over 64 channels. 4 pairs/block.
__global__ void k_dec(const float* __restrict__ h, float* __restrict__ out) {
    int k = blockIdx.x * 4 + (threadIdx.x >> 6);
    int j = threadIdx.x & 63;
    if (k >= N_NODES / 4) return;
    float u = h[(size_t)(4 * k) * HC + j];
    float v = h[(size_t)(4 * k + 1) * HC + j];
    float p = u * v;
    for (int off = 32; off > 0; off >>= 1) p += __shfl_down(p, off, 64);
    if (j == 0) out[k] = p;
}

// ---------------- launch ----------------
extern "C" void kernel_launch(void* const* d_in, const int* in_sizes, int n_in,
                              void* d_out, int out_size, void* d_ws, size_t ws_size,
                              hipStream_t stream) {
    const float* x       = (const float*)d_in[0];   // [N,4]
    const float* W0      = (const float*)d_in[1];   // [4,64]
    const float* W13     = (const float*)d_in[2];   // [3,64,64]
    const float* eemb    = (const float*)d_in[3];   // [4,5,64]
    const float* att_src = (const float*)d_in[4];   // [4,2,32]
    const float* att_dst = (const float*)d_in[5];   // [4,2,32]
    const float* bias    = (const float*)d_in[6];   // [4,64]
    const int*   eidx    = (const int*)d_in[7];     // [2,E]
    const int*   eattr   = (const int*)d_in[8];     // [E]
    float* out = (float*)d_out;

    const int* src = eidx;
    const int* dst = eidx + N_EDGES;

    // workspace layout
    char* wsb = (char*)d_ws;
    size_t off = 0;
    auto alloc = [&](size_t bytes) { char* p = wsb + off; off += (bytes + 255) & ~(size_t)255; return p; };
    float* hprev    = (float*)alloc((size_t)N_NODES * HC * 4);
    float* hcur     = (float*)alloc((size_t)N_NODES * HC * 4);
    float* ssrc     = (float*)alloc((size_t)N_NODES * 2 * 4);
    float* sdst     = (float*)alloc((size_t)N_NODES * 2 * 4);
    float* escore   = (float*)alloc(NLAYERS * ECLS * NHEADS * 4);
    int*   deg      = (int*)alloc((size_t)N_NODES * 4);
    int*   bscan    = (int*)alloc((size_t)N_NODES * 4);
    int*   rowstart = (int*)alloc(((size_t)N_NODES + 1) * 4);
    int*   cursor   = (int*)alloc((size_t)N_NODES * 4);
    int*   part     = (int*)alloc(SCAN_BLOCKS * 4);
    int*   packed   = (int*)alloc((size_t)N_EDGES * 4);

    const int edgeBlocks = (N_EDGES + 255) / 256;
    const int nodeBlocks = (N_NODES + 3) / 4;
    const int decBlocks  = (N_NODES / 4 + 3) / 4;

    // ---- CSR build (once per call) ----
    hipMemsetAsync(deg, 0, (size_t)N_NODES * 4, stream);
    k_hist<<<edgeBlocks, 256, 0, stream>>>(dst, deg);
    k_scan1<<<SCAN_BLOCKS, 256, 0, stream>>>(deg, bscan, part);
    k_scan2<<<1, 512, 0, stream>>>(part);
    k_scan3<<<SCAN_BLOCKS, 256, 0, stream>>>(deg, bscan, part, rowstart, cursor);
    k_scatter<<<edgeBlocks, 256, 0, stream>>>(src, dst, eattr, cursor, packed);

    k_escore<<<1, 64, 0, stream>>>(eemb, att_src, escore);

    for (int l = 0; l < NLAYERS; ++l) {
        const float* in  = (l == 0) ? x : hprev;
        int Fin          = (l == 0) ? 4 : HC;
        const float* W   = (l == 0) ? W0 : (W13 + (size_t)(l - 1) * HC * HC);
        const float* asr = att_src + l * HC;
        const float* ads = att_dst + l * HC;
        const float* el  = eemb + (size_t)l * ECLS * HC;
        const float* esl = escore + l * ECLS * NHEADS;
        const float* bl  = bias + l * HC;

        k_linear<<<nodeBlocks, 256, 0, stream>>>(in, Fin, W, asr, ads, hcur, ssrc, sdst);
        k_edge<<<nodeBlocks, 256, 0, stream>>>(rowstart, packed, ssrc, sdst, esl,
                                               hcur, el, bl, hprev);
    }

    k_dec<<<decBlocks, 256, 0, stream>>>(hprev, out);
}

// Round 3
// 796.261 us; speedup vs baseline: 3.7139x; 1.4969x over previous
//
#include <hip/hip_runtime.h>
#include <hip/hip_bf16.h>
#include <math.h>

#define N_NODES 100000
#define N_EDGES 1600000
#define HC 64          // H*C
#define NHEADS 2
#define NLAYERS 4
#define ECLS 5
#define SCAN_BLOCKS ((N_NODES + 255) / 256)   // 391

// ---------------- CSR build ----------------

__global__ void k_hist(const int* __restrict__ dst, int* __restrict__ deg) {
    int e = blockIdx.x * 256 + threadIdx.x;
    if (e < N_EDGES) atomicAdd(&deg[dst[e]], 1);
}

// Per-block inclusive scan; write block sums to part.
__global__ void k_scan1(const int* __restrict__ deg, int* __restrict__ bscan,
                        int* __restrict__ part) {
    __shared__ int tmp[256];
    int i = blockIdx.x * 256 + threadIdx.x;
    int v = (i < N_NODES) ? deg[i] : 0;
    tmp[threadIdx.x] = v;
    __syncthreads();
    for (int off = 1; off < 256; off <<= 1) {
        int t = (threadIdx.x >= off) ? tmp[threadIdx.x - off] : 0;
        __syncthreads();
        tmp[threadIdx.x] += t;
        __syncthreads();
    }
    if (i < N_NODES) bscan[i] = tmp[threadIdx.x];
    if (threadIdx.x == 255) part[blockIdx.x] = tmp[255];
}

// Single-block exclusive scan of block sums (SCAN_BLOCKS <= 512).
__global__ void k_scan2(int* __restrict__ part) {
    __shared__ int tmp[512];
    int tid = threadIdx.x;
    int v = (tid < SCAN_BLOCKS) ? part[tid] : 0;
    tmp[tid] = v;
    __syncthreads();
    for (int off = 1; off < 512; off <<= 1) {
        int t = (tid >= off) ? tmp[tid - off] : 0;
        __syncthreads();
        tmp[tid] += t;
        __syncthreads();
    }
    if (tid < SCAN_BLOCKS) part[tid] = tmp[tid] - v;   // exclusive
}

// rowstart[i] = global exclusive prefix; cursor copy for scatter.
__global__ void k_scan3(const int* __restrict__ deg, const int* __restrict__ bscan,
                        const int* __restrict__ part,
                        int* __restrict__ rowstart, int* __restrict__ cursor) {
    int i = blockIdx.x * 256 + threadIdx.x;
    if (i < N_NODES) {
        int ex = bscan[i] - deg[i] + part[blockIdx.x];
        rowstart[i] = ex;
        cursor[i] = ex;
    }
    if (i == 0) rowstart[N_NODES] = N_EDGES;
}

// Scatter edges into dst-sorted order; pack src (17b) | attr<<20.
__global__ void k_scatter(const int* __restrict__ src, const int* __restrict__ dst,
                          const int* __restrict__ attr,
                          int* __restrict__ cursor, int* __restrict__ packed) {
    int e = blockIdx.x * 256 + threadIdx.x;
    if (e >= N_EDGES) return;
    int d = dst[e];
    int pos = atomicAdd(&cursor[d], 1);
    packed[pos] = src[e] | (attr[e] << 20);
}

// ---------------- per-layer kernels ----------------

// escore[l][c][h] = dot(eemb[l][c][h*32..], att_src[l][h][..])
__global__ void k_escore(const float* __restrict__ eemb,
                         const float* __restrict__ att_src,
                         float* __restrict__ escore) {
    int idx = threadIdx.x;
    if (idx < NLAYERS * ECLS * NHEADS) {
        int l = idx / (ECLS * NHEADS);
        int r = idx % (ECLS * NHEADS);
        int c = r >> 1;
        int h = r & 1;
        float s = 0.f;
        const float* ev = eemb + l * ECLS * HC + c * HC + h * 32;
        const float* av = att_src + l * HC + h * 32;
        for (int k = 0; k < 32; ++k) s += ev[k] * av[k];
        escore[idx] = s;
    }
}

// hcur = in @ W ; per-node attention partials ssrc/sdst.
// Block = 256 threads = 4 nodes x 64 channels (one wave per node).
__global__ void k_linear(const float* __restrict__ in, int Fin,
                         const float* __restrict__ W,        // [Fin][64]
                         const float* __restrict__ asrc,     // [2][32]
                         const float* __restrict__ adst,     // [2][32]
                         float* __restrict__ hcur,
                         float* __restrict__ ssrc, float* __restrict__ sdst) {
    __shared__ float Wl[64 * 64];
    int tid = threadIdx.x;
    for (int i = tid; i < Fin * HC; i += 256) Wl[i] = W[i];
    __syncthreads();

    int n = blockIdx.x * 4 + (tid >> 6);
    int j = tid & 63;
    if (n >= N_NODES) return;

    const float* row = in + (size_t)n * Fin;
    float acc = 0.f;
    for (int k = 0; k < Fin; ++k) acc += row[k] * Wl[k * HC + j];
    hcur[(size_t)n * HC + j] = acc;

    int head = j >> 5;
    int c = j & 31;
    float ps = acc * asrc[head * 32 + c];
    float pd = acc * adst[head * 32 + c];
    for (int off = 16; off > 0; off >>= 1) {
        ps += __shfl_down(ps, off, 32);
        pd += __shfl_down(pd, off, 32);
    }
    if (c == 0) {
        ssrc[n * 2 + head] = ps;
        sdst[n * 2 + head] = pd;
    }
}

// Fused edge pipeline: one wave per dst node.
// Lane layout: sub = lane>>4 (edge slot 0..3), q = lane&15 (channels 4q..4q+3).
// 4 edges in flight per wave; plain softmax (no max-shift: logits are O(1)).
__global__ void k_edge(const int* __restrict__ rowstart, const int* __restrict__ packed,
                       const float* __restrict__ ssrc, const float* __restrict__ sdst,
                       const float* __restrict__ escore_l,   // [5][2]
                       const float* __restrict__ hcur,
                       const float* __restrict__ eemb_l,     // [5][64]
                       const float* __restrict__ bias_l,     // [64]
                       float* __restrict__ hnext) {
    int n = blockIdx.x * 4 + (threadIdx.x >> 6);
    if (n >= N_NODES) return;
    int lane = threadIdx.x & 63;
    int sub = lane >> 4;       // edge slot
    int q   = lane & 15;       // channel quad: channels 4q..4q+3
    int h   = q >> 3;          // head (channels 0..31 -> 0, 32..63 -> 1)

    int beg = rowstart[n];
    int end = rowstart[n + 1];
    float sd = sdst[n * 2 + h];

    float4 acc = make_float4(0.f, 0.f, 0.f, 0.f);
    float ssum = 0.f;
    for (int i = beg + sub; i < end; i += 4) {
        int p = packed[i];
        int s = p & 0xFFFFF;
        int a = p >> 20;
        float lg = sd + ssrc[s * 2 + h] + escore_l[a * 2 + h];
        lg = lg >= 0.f ? lg : 0.2f * lg;
        float w = __expf(lg);
        float4 hv = *(const float4*)(hcur + (size_t)s * HC + q * 4);
        float4 ev = *(const float4*)(eemb_l + a * HC + q * 4);
        acc.x += w * (hv.x + ev.x);
        acc.y += w * (hv.y + ev.y);
        acc.z += w * (hv.z + ev.z);
        acc.w += w * (hv.w + ev.w);
        ssum += w;
    }
    // reduce the 4 edge slots (lanes differing in bits 4,5; q/head preserved)
    for (int off = 16; off < 64; off <<= 1) {
        acc.x += __shfl_xor(acc.x, off, 64);
        acc.y += __shfl_xor(acc.y, off, 64);
        acc.z += __shfl_xor(acc.z, off, 64);
        acc.w += __shfl_xor(acc.w, off, 64);
        ssum  += __shfl_xor(ssum,  off, 64);
    }
    if (sub == 0) {
        float inv = 1.f / (ssum + 1e-16f);
        float4 bv = *(const float4*)(bias_l + q * 4);
        float4 o;
        o.x = acc.x * inv + bv.x;  o.x = o.x > 0.f ? o.x : expm1f(o.x);
        o.y = acc.y * inv + bv.y;  o.y = o.y > 0.f ? o.y : expm1f(o.y);
        o.z = acc.z * inv + bv.z;  o.z = o.z > 0.f ? o.z : expm1f(o.z);
        o.w = acc.w * inv + bv.w;  o.w = o.w > 0.f ? o.w : expm1f(o.w);
        *(float4*)(hnext + (size_t)n * HC + q * 4) = o;
    }
}

// Decoder: out[k] = dot(h[4k], h[4k+1]) over 64 channels. 4 pairs/block.
__global__ void k_dec(const float* __restrict__ h, float* __restrict__ out) {
    int k = blockIdx.x * 4 + (threadIdx.x >> 6);
    int j = threadIdx.x & 63;
    if (k >= N_NODES / 4) return;
    float u = h[(size_t)(4 * k) * HC + j];
    float v = h[(size_t)(4 * k + 1) * HC + j];
    float p = u * v;
    for (int off = 32; off > 0; off >>= 1) p += __shfl_down(p, off, 64);
    if (j == 0) out[k] = p;
}

// ---------------- launch ----------------
extern "C" void kernel_launch(void* const* d_in, const int* in_sizes, int n_in,
                              void* d_out, int out_size, void* d_ws, size_t ws_size,
                              hipStream_t stream) {
    const float* x       = (const float*)d_in[0];   // [N,4]
    const float* W0      = (const float*)d_in[1];   // [4,64]
    const float* W13     = (const float*)d_in[2];   // [3,64,64]
    const float* eemb    = (const float*)d_in[3];   // [4,5,64]
    const float* att_src = (const float*)d_in[4];   // [4,2,32]
    const float* att_dst = (const float*)d_in[5];   // [4,2,32]
    const float* bias    = (const float*)d_in[6];   // [4,64]
    const int*   eidx    = (const int*)d_in[7];     // [2,E]
    const int*   eattr   = (const int*)d_in[8];     // [E]
    float* out = (float*)d_out;

    const int* src = eidx;
    const int* dst = eidx + N_EDGES;

    // workspace layout
    char* wsb = (char*)d_ws;
    size_t off = 0;
    auto alloc = [&](size_t bytes) { char* p = wsb + off; off += (bytes + 255) & ~(size_t)255; return p; };
    float* hprev    = (float*)alloc((size_t)N_NODES * HC * 4);
    float* hcur     = (float*)alloc((size_t)N_NODES * HC * 4);
    float* ssrc     = (float*)alloc((size_t)N_NODES * 2 * 4);
    float* sdst     = (float*)alloc((size_t)N_NODES * 2 * 4);
    float* escore   = (float*)alloc(NLAYERS * ECLS * NHEADS * 4);
    int*   deg      = (int*)alloc((size_t)N_NODES * 4);
    int*   bscan    = (int*)alloc((size_t)N_NODES * 4);
    int*   rowstart = (int*)alloc(((size_t)N_NODES + 1) * 4);
    int*   cursor   = (int*)alloc((size_t)N_NODES * 4);
    int*   part     = (int*)alloc(SCAN_BLOCKS * 4);
    int*   packed   = (int*)alloc((size_t)N_EDGES * 4);

    const int edgeBlocks = (N_EDGES + 255) / 256;
    const int nodeBlocks = (N_NODES + 3) / 4;
    const int decBlocks  = (N_NODES / 4 + 3) / 4;

    // ---- CSR build (once per call) ----
    hipMemsetAsync(deg, 0, (size_t)N_NODES * 4, stream);
    k_hist<<<edgeBlocks, 256, 0, stream>>>(dst, deg);
    k_scan1<<<SCAN_BLOCKS, 256, 0, stream>>>(deg, bscan, part);
    k_scan2<<<1, 512, 0, stream>>>(part);
    k_scan3<<<SCAN_BLOCKS, 256, 0, stream>>>(deg, bscan, part, rowstart, cursor);
    k_scatter<<<edgeBlocks, 256, 0, stream>>>(src, dst, eattr, cursor, packed);

    k_escore<<<1, 64, 0, stream>>>(eemb, att_src, escore);

    for (int l = 0; l < NLAYERS; ++l) {
        const float* in  = (l == 0) ? x : hprev;
        int Fin          = (l == 0) ? 4 : HC;
        const float* W   = (l == 0) ? W0 : (W13 + (size_t)(l - 1) * HC * HC);
        const float* asr = att_src + l * HC;
        const float* ads = att_dst + l * HC;
        const float* el  = eemb + (size_t)l * ECLS * HC;
        const float* esl = escore + l * ECLS * NHEADS;
        const float* bl  = bias + l * HC;

        k_linear<<<nodeBlocks, 256, 0, stream>>>(in, Fin, W, asr, ads, hcur, ssrc, sdst);
        k_edge<<<nodeBlocks, 256, 0, stream>>>(rowstart, packed, ssrc, sdst, esl,
                                               hcur, el, bl, hprev);
    }

    k_dec<<<decBlocks, 256, 0, stream>>>(hprev, out);
}

// Round 4
// 684.153 us; speedup vs baseline: 4.3224x; 1.1639x over previous
//
#include <hip/hip_runtime.h>
#include <hip/hip_bf16.h>
#include <math.h>

#define N_NODES 100000
#define N_EDGES 1600000
#define HC 64          // H*C
#define NHEADS 2
#define NLAYERS 4
#define ECLS 5
#define NBUCK 196              // ceil(N / 512); bucket = dst >> 9
#define NBLK 256               // coarse pass blocks
#define EPB (N_EDGES / NBLK)   // 6250 edges per coarse block (exact)

// ---------------- CSR build: two-level bucket sort, no global atomics ------

// P1: per-(bucket,block) counts. Block b handles edges [b*EPB, (b+1)*EPB).
__global__ void k_chist(const int* __restrict__ dst, int* __restrict__ bh) {
    __shared__ int lh[NBUCK];
    int tid = threadIdx.x, blk = blockIdx.x;
    for (int i = tid; i < NBUCK; i += 256) lh[i] = 0;
    __syncthreads();
    int s = blk * EPB, e = s + EPB;
    for (int i = s + tid; i < e; i += 256) atomicAdd(&lh[dst[i] >> 9], 1);
    __syncthreads();
    for (int i = tid; i < NBUCK; i += 256) bh[i * 256 + blk] = lh[i];
}

// P2a: per-256-tile exclusive scan of flat bh (bucket-major) -> bbase, tile sums -> part.
__global__ void k_s1(const int* __restrict__ bh, int* __restrict__ bbase,
                     int* __restrict__ part) {
    __shared__ int tmp[256];
    int tid = threadIdx.x;
    int i = blockIdx.x * 256 + tid;
    int v = bh[i];
    tmp[tid] = v;
    __syncthreads();
    for (int off = 1; off < 256; off <<= 1) {
        int t = (tid >= off) ? tmp[tid - off] : 0;
        __syncthreads();
        tmp[tid] += t;
        __syncthreads();
    }
    bbase[i] = tmp[tid] - v;
    if (tid == 255) part[blockIdx.x] = tmp[255];
}

// P2b: exclusive scan of the NBUCK tile sums (one tile per bucket); total -> gbase[NBUCK].
__global__ void k_s2(int* __restrict__ part, int* __restrict__ gbase) {
    __shared__ int tmp[256];
    int tid = threadIdx.x;
    int v = (tid < NBUCK) ? part[tid] : 0;
    tmp[tid] = v;
    __syncthreads();
    for (int off = 1; off < 256; off <<= 1) {
        int t = (tid >= off) ? tmp[tid - off] : 0;
        __syncthreads();
        tmp[tid] += t;
        __syncthreads();
    }
    if (tid < NBUCK) part[tid] = tmp[tid] - v;
    if (tid == 255) gbase[NBUCK] = tmp[255];
}

// P2c: add tile bases -> global exclusive base per (bucket,block); bucket bases -> gbase.
__global__ void k_s3(int* __restrict__ bbase, const int* __restrict__ part,
                     int* __restrict__ gbase) {
    int tid = threadIdx.x;
    int i = blockIdx.x * 256 + tid;
    int v = bbase[i] + part[blockIdx.x];
    bbase[i] = v;
    if (tid == 0) gbase[blockIdx.x] = v;   // flat index bucket*256 + block0
}

// P3: coarse scatter into bucket-grouped array. Deterministic region per
// (bucket,block); ranks via LDS atomics only.
__global__ void k_cscatter(const int* __restrict__ src, const int* __restrict__ dst,
                           const int* __restrict__ attr, const int* __restrict__ bbase,
                           int* __restrict__ bkt) {
    __shared__ int cur[NBUCK];
    int tid = threadIdx.x, blk = blockIdx.x;
    for (int i = tid; i < NBUCK; i += 256) cur[i] = bbase[i * 256 + blk];
    __syncthreads();
    int s0 = blk * EPB, e0 = s0 + EPB;
    for (int i = s0 + tid; i < e0; i += 256) {
        int d = dst[i];
        int b = d >> 9;
        int pos = atomicAdd(&cur[b], 1);
        bkt[pos] = src[i] | (attr[i] << 17) | ((d & 511) << 20);
    }
}

// P4: fine sort within each bucket (512 nodes); emits final packed + rowstart.
__global__ void k_fine(const int* __restrict__ gbase, const int* __restrict__ bkt,
                       int* __restrict__ packed, int* __restrict__ rowstart) {
    __shared__ int hist[512];
    __shared__ int cur[512];
    int b = blockIdx.x, tid = threadIdx.x;   // 512 threads
    int base = gbase[b];
    int nb = gbase[b + 1] - base;
    hist[tid] = 0;
    __syncthreads();
    for (int i = tid; i < nb; i += 512)
        atomicAdd(&hist[(bkt[base + i] >> 20) & 0x1FF], 1);
    __syncthreads();
    int v = hist[tid];
    for (int off = 1; off < 512; off <<= 1) {
        int t = (tid >= off) ? hist[tid - off] : 0;
        __syncthreads();
        hist[tid] += t;
        __syncthreads();
    }
    int excl = hist[tid] - v;
    int node = (b << 9) + tid;
    if (node <= N_NODES) rowstart[node] = base + excl;   // node==N -> E
    cur[tid] = excl;
    __syncthreads();
    for (int i = tid; i < nb; i += 512) {
        int p = bkt[base + i];
        int r = atomicAdd(&cur[(p >> 20) & 0x1FF], 1);
        packed[base + r] = p;
    }
}

// ---------------- per-layer kernels ----------------

// escore[l][c][h] = dot(eemb[l][c][h*32..], att_src[l][h][..])
__global__ void k_escore(const float* __restrict__ eemb,
                         const float* __restrict__ att_src,
                         float* __restrict__ escore) {
    int idx = threadIdx.x;
    if (idx < NLAYERS * ECLS * NHEADS) {
        int l = idx / (ECLS * NHEADS);
        int r = idx % (ECLS * NHEADS);
        int c = r >> 1;
        int h = r & 1;
        float s = 0.f;
        const float* ev = eemb + l * ECLS * HC + c * HC + h * 32;
        const float* av = att_src + l * HC + h * 32;
        for (int k = 0; k < 32; ++k) s += ev[k] * av[k];
        escore[idx] = s;
    }
}

// hcur = in @ W ; per-node attention partials ssrc/sdst.
__global__ void k_linear(const float* __restrict__ in, int Fin,
                         const float* __restrict__ W,        // [Fin][64]
                         const float* __restrict__ asrc,     // [2][32]
                         const float* __restrict__ adst,     // [2][32]
                         float* __restrict__ hcur,
                         float* __restrict__ ssrc, float* __restrict__ sdst) {
    __shared__ float Wl[64 * 64];
    int tid = threadIdx.x;
    for (int i = tid; i < Fin * HC; i += 256) Wl[i] = W[i];
    __syncthreads();

    int n = blockIdx.x * 4 + (tid >> 6);
    int j = tid & 63;
    if (n >= N_NODES) return;

    const float* row = in + (size_t)n * Fin;
    float acc = 0.f;
    for (int k = 0; k < Fin; ++k) acc += row[k] * Wl[k * HC + j];
    hcur[(size_t)n * HC + j] = acc;

    int head = j >> 5;
    int c = j & 31;
    float ps = acc * asrc[head * 32 + c];
    float pd = acc * adst[head * 32 + c];
    for (int off = 16; off > 0; off >>= 1) {
        ps += __shfl_down(ps, off, 32);
        pd += __shfl_down(pd, off, 32);
    }
    if (c == 0) {
        ssrc[n * 2 + head] = ps;
        sdst[n * 2 + head] = pd;
    }
}

// Fused edge pipeline: one wave per dst node.
// Lane layout: sub = lane>>4 (edge slot 0..3), q = lane&15 (channels 4q..4q+3).
__global__ void k_edge(const int* __restrict__ rowstart, const int* __restrict__ packed,
                       const float* __restrict__ ssrc, const float* __restrict__ sdst,
                       const float* __restrict__ escore_l,   // [5][2]
                       const float* __restrict__ hcur,
                       const float* __restrict__ eemb_l,     // [5][64]
                       const float* __restrict__ bias_l,     // [64]
                       float* __restrict__ hnext) {
    int n = blockIdx.x * 4 + (threadIdx.x >> 6);
    if (n >= N_NODES) return;
    int lane = threadIdx.x & 63;
    int sub = lane >> 4;       // edge slot
    int q   = lane & 15;       // channel quad
    int h   = q >> 3;          // head

    int beg = rowstart[n];
    int end = rowstart[n + 1];
    float sd = sdst[n * 2 + h];

    float4 acc = make_float4(0.f, 0.f, 0.f, 0.f);
    float ssum = 0.f;
    for (int i = beg + sub; i < end; i += 4) {
        int p = packed[i];
        int s = p & 0x1FFFF;
        int a = (p >> 17) & 7;
        float lg = sd + ssrc[s * 2 + h] + escore_l[a * 2 + h];
        lg = lg >= 0.f ? lg : 0.2f * lg;
        float w = __expf(lg);
        float4 hv = *(const float4*)(hcur + (size_t)s * HC + q * 4);
        float4 ev = *(const float4*)(eemb_l + a * HC + q * 4);
        acc.x += w * (hv.x + ev.x);
        acc.y += w * (hv.y + ev.y);
        acc.z += w * (hv.z + ev.z);
        acc.w += w * (hv.w + ev.w);
        ssum += w;
    }
    for (int off = 16; off < 64; off <<= 1) {
        acc.x += __shfl_xor(acc.x, off, 64);
        acc.y += __shfl_xor(acc.y, off, 64);
        acc.z += __shfl_xor(acc.z, off, 64);
        acc.w += __shfl_xor(acc.w, off, 64);
        ssum  += __shfl_xor(ssum,  off, 64);
    }
    if (sub == 0) {
        float inv = 1.f / (ssum + 1e-16f);
        float4 bv = *(const float4*)(bias_l + q * 4);
        float4 o;
        o.x = acc.x * inv + bv.x;  o.x = o.x > 0.f ? o.x : expm1f(o.x);
        o.y = acc.y * inv + bv.y;  o.y = o.y > 0.f ? o.y : expm1f(o.y);
        o.z = acc.z * inv + bv.z;  o.z = o.z > 0.f ? o.z : expm1f(o.z);
        o.w = acc.w * inv + bv.w;  o.w = o.w > 0.f ? o.w : expm1f(o.w);
        *(float4*)(hnext + (size_t)n * HC + q * 4) = o;
    }
}

// Decoder: out[k] = dot(h[4k], h[4k+1]) over 64 channels. 4 pairs/block.
__global__ void k_dec(const float* __restrict__ h, float* __restrict__ out) {
    int k = blockIdx.x * 4 + (threadIdx.x >> 6);
    int j = threadIdx.x & 63;
    if (k >= N_NODES / 4) return;
    float u = h[(size_t)(4 * k) * HC + j];
    float v = h[(size_t)(4 * k + 1) * HC + j];
    float p = u * v;
    for (int off = 32; off > 0; off >>= 1) p += __shfl_down(p, off, 64);
    if (j == 0) out[k] = p;
}

// ---------------- launch ----------------
extern "C" void kernel_launch(void* const* d_in, const int* in_sizes, int n_in,
                              void* d_out, int out_size, void* d_ws, size_t ws_size,
                              hipStream_t stream) {
    const float* x       = (const float*)d_in[0];   // [N,4]
    const float* W0      = (const float*)d_in[1];   // [4,64]
    const float* W13     = (const float*)d_in[2];   // [3,64,64]
    const float* eemb    = (const float*)d_in[3];   // [4,5,64]
    const float* att_src = (const float*)d_in[4];   // [4,2,32]
    const float* att_dst = (const float*)d_in[5];   // [4,2,32]
    const float* bias    = (const float*)d_in[6];   // [4,64]
    const int*   eidx    = (const int*)d_in[7];     // [2,E]
    const int*   eattr   = (const int*)d_in[8];     // [E]
    float* out = (float*)d_out;

    const int* src = eidx;
    const int* dst = eidx + N_EDGES;

    // workspace layout
    char* wsb = (char*)d_ws;
    size_t off = 0;
    auto alloc = [&](size_t bytes) { char* p = wsb + off; off += (bytes + 255) & ~(size_t)255; return p; };
    float* hprev    = (float*)alloc((size_t)N_NODES * HC * 4);
    float* hcur     = (float*)alloc((size_t)N_NODES * HC * 4);
    float* ssrc     = (float*)alloc((size_t)N_NODES * 2 * 4);
    float* sdst     = (float*)alloc((size_t)N_NODES * 2 * 4);
    float* escore   = (float*)alloc(NLAYERS * ECLS * NHEADS * 4);
    int*   bh       = (int*)alloc((size_t)NBUCK * 256 * 4);
    int*   bbase    = (int*)alloc((size_t)NBUCK * 256 * 4);
    int*   part     = (int*)alloc(256 * 4);
    int*   gbase    = (int*)alloc((NBUCK + 1) * 4);
    int*   rowstart = (int*)alloc(((size_t)N_NODES + 1) * 4);
    int*   bkt      = (int*)alloc((size_t)N_EDGES * 4);
    int*   packed   = (int*)alloc((size_t)N_EDGES * 4);

    const int nodeBlocks = (N_NODES + 3) / 4;
    const int decBlocks  = (N_NODES / 4 + 3) / 4;

    // ---- CSR build: bucket sort, no global atomics ----
    k_chist<<<NBLK, 256, 0, stream>>>(dst, bh);
    k_s1<<<NBUCK, 256, 0, stream>>>(bh, bbase, part);
    k_s2<<<1, 256, 0, stream>>>(part, gbase);
    k_s3<<<NBUCK, 256, 0, stream>>>(bbase, part, gbase);
    k_cscatter<<<NBLK, 256, 0, stream>>>(src, dst, eattr, bbase, bkt);
    k_fine<<<NBUCK, 512, 0, stream>>>(gbase, bkt, packed, rowstart);

    k_escore<<<1, 64, 0, stream>>>(eemb, att_src, escore);

    for (int l = 0; l < NLAYERS; ++l) {
        const float* in  = (l == 0) ? x : hprev;
        int Fin          = (l == 0) ? 4 : HC;
        const float* W   = (l == 0) ? W0 : (W13 + (size_t)(l - 1) * HC * HC);
        const float* asr = att_src + l * HC;
        const float* ads = att_dst + l * HC;
        const float* el  = eemb + (size_t)l * ECLS * HC;
        const float* esl = escore + l * ECLS * NHEADS;
        const float* bl  = bias + l * HC;

        k_linear<<<nodeBlocks, 256, 0, stream>>>(in, Fin, W, asr, ads, hcur, ssrc, sdst);
        k_edge<<<nodeBlocks, 256, 0, stream>>>(rowstart, packed, ssrc, sdst, esl,
                                               hcur, el, bl, hprev);
    }

    k_dec<<<decBlocks, 256, 0, stream>>>(hprev, out);
}

// Round 5
// 628.633 us; speedup vs baseline: 4.7042x; 1.0883x over previous
//
#include <hip/hip_runtime.h>
#include <hip/hip_bf16.h>
#include <math.h>

#define N_NODES 100000
#define N_EDGES 1600000
#define HC 64          // H*C
#define NHEADS 2
#define NLAYERS 4
#define ECLS 5
#define NBUCK 196              // ceil(N / 512); bucket = dst >> 9
#define NBLK 256               // coarse pass blocks
#define EPB (N_EDGES / NBLK)   // 6250 edges per coarse block (exact)

// ---------------- CSR build: two-level bucket sort, no global atomics ------

// P1: per-(bucket,block) counts. Block b handles edges [b*EPB, (b+1)*EPB).
__global__ void k_chist(const int* __restrict__ dst, int* __restrict__ bh) {
    __shared__ int lh[NBUCK];
    int tid = threadIdx.x, blk = blockIdx.x;
    for (int i = tid; i < NBUCK; i += 256) lh[i] = 0;
    __syncthreads();
    int s = blk * EPB, e = s + EPB;
    for (int i = s + tid; i < e; i += 256) atomicAdd(&lh[dst[i] >> 9], 1);
    __syncthreads();
    for (int i = tid; i < NBUCK; i += 256) bh[i * 256 + blk] = lh[i];
}

// P2a: per-256-tile exclusive scan of flat bh (bucket-major) -> bbase, tile sums -> part.
__global__ void k_s1(const int* __restrict__ bh, int* __restrict__ bbase,
                     int* __restrict__ part) {
    __shared__ int tmp[256];
    int tid = threadIdx.x;
    int i = blockIdx.x * 256 + tid;
    int v = bh[i];
    tmp[tid] = v;
    __syncthreads();
    for (int off = 1; off < 256; off <<= 1) {
        int t = (tid >= off) ? tmp[tid - off] : 0;
        __syncthreads();
        tmp[tid] += t;
        __syncthreads();
    }
    bbase[i] = tmp[tid] - v;
    if (tid == 255) part[blockIdx.x] = tmp[255];
}

// P2b: exclusive scan of the NBUCK tile sums; total -> gbase[NBUCK].
// Also computes escore[l][c][h] (folded in to save a launch).
__global__ void k_s2(int* __restrict__ part, int* __restrict__ gbase,
                     const float* __restrict__ eemb, const float* __restrict__ att_src,
                     float* __restrict__ escore) {
    __shared__ int tmp[256];
    int tid = threadIdx.x;
    int v = (tid < NBUCK) ? part[tid] : 0;
    tmp[tid] = v;
    __syncthreads();
    for (int off = 1; off < 256; off <<= 1) {
        int t = (tid >= off) ? tmp[tid - off] : 0;
        __syncthreads();
        tmp[tid] += t;
        __syncthreads();
    }
    if (tid < NBUCK) part[tid] = tmp[tid] - v;
    if (tid == 255) gbase[NBUCK] = tmp[255];
    if (tid >= 200 && tid < 200 + NLAYERS * ECLS * NHEADS) {
        int idx = tid - 200;
        int l = idx / (ECLS * NHEADS);
        int r = idx % (ECLS * NHEADS);
        int c = r >> 1;
        int h = r & 1;
        float s = 0.f;
        const float* ev = eemb + l * ECLS * HC + c * HC + h * 32;
        const float* av = att_src + l * HC + h * 32;
        for (int k = 0; k < 32; ++k) s += ev[k] * av[k];
        escore[idx] = s;
    }
}

// P2c: add tile bases -> global exclusive base per (bucket,block); bucket bases -> gbase.
__global__ void k_s3(int* __restrict__ bbase, const int* __restrict__ part,
                     int* __restrict__ gbase) {
    int tid = threadIdx.x;
    int i = blockIdx.x * 256 + tid;
    int v = bbase[i] + part[blockIdx.x];
    bbase[i] = v;
    if (tid == 0) gbase[blockIdx.x] = v;
}

// P3: coarse scatter into bucket-grouped array; LDS atomics only.
__global__ void k_cscatter(const int* __restrict__ src, const int* __restrict__ dst,
                           const int* __restrict__ attr, const int* __restrict__ bbase,
                           int* __restrict__ bkt) {
    __shared__ int cur[NBUCK];
    int tid = threadIdx.x, blk = blockIdx.x;
    for (int i = tid; i < NBUCK; i += 256) cur[i] = bbase[i * 256 + blk];
    __syncthreads();
    int s0 = blk * EPB, e0 = s0 + EPB;
    for (int i = s0 + tid; i < e0; i += 256) {
        int d = dst[i];
        int b = d >> 9;
        int pos = atomicAdd(&cur[b], 1);
        bkt[pos] = src[i] | (attr[i] << 17) | ((d & 511) << 20);
    }
}

// P4: fine sort within each bucket (512 nodes); emits final packed + rowstart.
__global__ void k_fine(const int* __restrict__ gbase, const int* __restrict__ bkt,
                       int* __restrict__ packed, int* __restrict__ rowstart) {
    __shared__ int hist[512];
    __shared__ int cur[512];
    int b = blockIdx.x, tid = threadIdx.x;   // 512 threads
    int base = gbase[b];
    int nb = gbase[b + 1] - base;
    hist[tid] = 0;
    __syncthreads();
    for (int i = tid; i < nb; i += 512)
        atomicAdd(&hist[(bkt[base + i] >> 20) & 0x1FF], 1);
    __syncthreads();
    int v = hist[tid];
    for (int off = 1; off < 512; off <<= 1) {
        int t = (tid >= off) ? hist[tid - off] : 0;
        __syncthreads();
        hist[tid] += t;
        __syncthreads();
    }
    int excl = hist[tid] - v;
    int node = (b << 9) + tid;
    if (node <= N_NODES) rowstart[node] = base + excl;
    cur[tid] = excl;
    __syncthreads();
    for (int i = tid; i < nb; i += 512) {
        int p = bkt[base + i];
        int r = atomicAdd(&cur[(p >> 20) & 0x1FF], 1);
        packed[base + r] = p;
    }
}

// ---------------- per-layer kernels ----------------

// hcur = in @ W ; per-node attention partials ssrc/sdst.
// Block = 256 threads = 4 nodes x 64 channels (one wave per node).
__global__ void k_linear(const float* __restrict__ in, int Fin,
                         const float* __restrict__ W,        // [Fin][64]
                         const float* __restrict__ asrc,     // [2][32]
                         const float* __restrict__ adst,     // [2][32]
                         float* __restrict__ hcur,
                         float* __restrict__ ssrc, float* __restrict__ sdst) {
    __shared__ float Wl[64 * 64];
    int tid = threadIdx.x;
    int nv = (Fin * HC) >> 2;
    for (int i = tid; i < nv; i += 256)
        ((float4*)Wl)[i] = ((const float4*)W)[i];
    __syncthreads();

    int n = blockIdx.x * 4 + (tid >> 6);
    int j = tid & 63;
    if (n >= N_NODES) return;

    const float* row = in + (size_t)n * Fin;
    float acc = 0.f;
    if (Fin == HC) {
        const float4* r4 = (const float4*)row;
        #pragma unroll
        for (int k4 = 0; k4 < 16; ++k4) {
            float4 r = r4[k4];
            acc += r.x * Wl[(k4 * 4 + 0) * HC + j];
            acc += r.y * Wl[(k4 * 4 + 1) * HC + j];
            acc += r.z * Wl[(k4 * 4 + 2) * HC + j];
            acc += r.w * Wl[(k4 * 4 + 3) * HC + j];
        }
    } else {
        for (int k = 0; k < Fin; ++k) acc += row[k] * Wl[k * HC + j];
    }
    hcur[(size_t)n * HC + j] = acc;

    int head = j >> 5;
    int c = j & 31;
    float ps = acc * asrc[head * 32 + c];
    float pd = acc * adst[head * 32 + c];
    for (int off = 16; off > 0; off >>= 1) {
        ps += __shfl_down(ps, off, 32);
        pd += __shfl_down(pd, off, 32);
    }
    if (c == 0) {
        ssrc[n * 2 + head] = ps;
        sdst[n * 2 + head] = pd;
    }
}

// Fused edge pipeline: one wave per dst node.
// Lane layout: sub = lane>>3 (edge slot 0..7), q = lane&7 (channels 8q..8q+7).
// 8 edges in flight per wave; plain softmax (logits are O(1), no max-shift).
__global__ void k_edge(const int* __restrict__ rowstart, const int* __restrict__ packed,
                       const float* __restrict__ ssrc, const float* __restrict__ sdst,
                       const float* __restrict__ escore_l,   // [5][2]
                       const float* __restrict__ hcur,
                       const float* __restrict__ eemb_l,     // [5][64]
                       const float* __restrict__ bias_l,     // [64]
                       float* __restrict__ hnext) {
    int n = blockIdx.x * 4 + (threadIdx.x >> 6);
    if (n >= N_NODES) return;
    int lane = threadIdx.x & 63;
    int sub = lane >> 3;       // edge slot 0..7
    int q   = lane & 7;        // channel octet: channels 8q..8q+7
    int h   = q >> 2;          // head (q<4 -> ch<32 -> head0)

    int beg = rowstart[n];
    int end = rowstart[n + 1];
    float sd = sdst[n * 2 + h];

    float4 a0 = make_float4(0.f, 0.f, 0.f, 0.f);
    float4 a1 = make_float4(0.f, 0.f, 0.f, 0.f);
    float ssum = 0.f;
    for (int i = beg + sub; i < end; i += 8) {
        int p = packed[i];
        int s = p & 0x1FFFF;
        int a = (p >> 17) & 7;
        float lg = sd + ssrc[s * 2 + h] + escore_l[a * 2 + h];
        lg = lg >= 0.f ? lg : 0.2f * lg;
        float w = __expf(lg);
        const float4* hp = (const float4*)(hcur + (size_t)s * HC + q * 8);
        const float4* ep = (const float4*)(eemb_l + a * HC + q * 8);
        float4 h0 = hp[0], h1 = hp[1];
        float4 e0 = ep[0], e1 = ep[1];
        a0.x += w * (h0.x + e0.x);
        a0.y += w * (h0.y + e0.y);
        a0.z += w * (h0.z + e0.z);
        a0.w += w * (h0.w + e0.w);
        a1.x += w * (h1.x + e1.x);
        a1.y += w * (h1.y + e1.y);
        a1.z += w * (h1.z + e1.z);
        a1.w += w * (h1.w + e1.w);
        ssum += w;
    }
    // reduce the 8 edge slots (lanes differing in bits 3,4,5; q/head preserved)
    for (int off = 8; off < 64; off <<= 1) {
        a0.x += __shfl_xor(a0.x, off, 64);
        a0.y += __shfl_xor(a0.y, off, 64);
        a0.z += __shfl_xor(a0.z, off, 64);
        a0.w += __shfl_xor(a0.w, off, 64);
        a1.x += __shfl_xor(a1.x, off, 64);
        a1.y += __shfl_xor(a1.y, off, 64);
        a1.z += __shfl_xor(a1.z, off, 64);
        a1.w += __shfl_xor(a1.w, off, 64);
        ssum  += __shfl_xor(ssum,  off, 64);
    }
    if (sub == 0) {
        float inv = 1.f / (ssum + 1e-16f);
        const float4* bp = (const float4*)(bias_l + q * 8);
        float4 b0 = bp[0], b1 = bp[1];
        float4 o0, o1;
        o0.x = a0.x * inv + b0.x;  o0.x = o0.x > 0.f ? o0.x : expm1f(o0.x);
        o0.y = a0.y * inv + b0.y;  o0.y = o0.y > 0.f ? o0.y : expm1f(o0.y);
        o0.z = a0.z * inv + b0.z;  o0.z = o0.z > 0.f ? o0.z : expm1f(o0.z);
        o0.w = a0.w * inv + b0.w;  o0.w = o0.w > 0.f ? o0.w : expm1f(o0.w);
        o1.x = a1.x * inv + b1.x;  o1.x = o1.x > 0.f ? o1.x : expm1f(o1.x);
        o1.y = a1.y * inv + b1.y;  o1.y = o1.y > 0.f ? o1.y : expm1f(o1.y);
        o1.z = a1.z * inv + b1.z;  o1.z = o1.z > 0.f ? o1.z : expm1f(o1.z);
        o1.w = a1.w * inv + b1.w;  o1.w = o1.w > 0.f ? o1.w : expm1f(o1.w);
        float4* op = (float4*)(hnext + (size_t)n * HC + q * 8);
        op[0] = o0;
        op[1] = o1;
    }
}

// Decoder: out[k] = dot(h[4k], h[4k+1]) over 64 channels. 4 pairs/block.
__global__ void k_dec(const float* __restrict__ h, float* __restrict__ out) {
    int k = blockIdx.x * 4 + (threadIdx.x >> 6);
    int j = threadIdx.x & 63;
    if (k >= N_NODES / 4) return;
    float u = h[(size_t)(4 * k) * HC + j];
    float v = h[(size_t)(4 * k + 1) * HC + j];
    float p = u * v;
    for (int off = 32; off > 0; off >>= 1) p += __shfl_down(p, off, 64);
    if (j == 0) out[k] = p;
}

// ---------------- launch ----------------
extern "C" void kernel_launch(void* const* d_in, const int* in_sizes, int n_in,
                              void* d_out, int out_size, void* d_ws, size_t ws_size,
                              hipStream_t stream) {
    const float* x       = (const float*)d_in[0];   // [N,4]
    const float* W0      = (const float*)d_in[1];   // [4,64]
    const float* W13     = (const float*)d_in[2];   // [3,64,64]
    const float* eemb    = (const float*)d_in[3];   // [4,5,64]
    const float* att_src = (const float*)d_in[4];   // [4,2,32]
    const float* att_dst = (const float*)d_in[5];   // [4,2,32]
    const float* bias    = (const float*)d_in[6];   // [4,64]
    const int*   eidx    = (const int*)d_in[7];     // [2,E]
    const int*   eattr   = (const int*)d_in[8];     // [E]
    float* out = (float*)d_out;

    const int* src = eidx;
    const int* dst = eidx + N_EDGES;

    // workspace layout
    char* wsb = (char*)d_ws;
    size_t off = 0;
    auto alloc = [&](size_t bytes) { char* p = wsb + off; off += (bytes + 255) & ~(size_t)255; return p; };
    float* hprev    = (float*)alloc((size_t)N_NODES * HC * 4);
    float* hcur     = (float*)alloc((size_t)N_NODES * HC * 4);
    float* ssrc     = (float*)alloc((size_t)N_NODES * 2 * 4);
    float* sdst     = (float*)alloc((size_t)N_NODES * 2 * 4);
    float* escore   = (float*)alloc(NLAYERS * ECLS * NHEADS * 4);
    int*   bh       = (int*)alloc((size_t)NBUCK * 256 * 4);
    int*   bbase    = (int*)alloc((size_t)NBUCK * 256 * 4);
    int*   part     = (int*)alloc(256 * 4);
    int*   gbase    = (int*)alloc((NBUCK + 1) * 4);
    int*   rowstart = (int*)alloc(((size_t)N_NODES + 1) * 4);
    int*   bkt      = (int*)alloc((size_t)N_EDGES * 4);
    int*   packed   = (int*)alloc((size_t)N_EDGES * 4);

    const int nodeBlocks = (N_NODES + 3) / 4;
    const int decBlocks  = (N_NODES / 4 + 3) / 4;

    // ---- CSR build: bucket sort, no global atomics ----
    k_chist<<<NBLK, 256, 0, stream>>>(dst, bh);
    k_s1<<<NBUCK, 256, 0, stream>>>(bh, bbase, part);
    k_s2<<<1, 256, 0, stream>>>(part, gbase, eemb, att_src, escore);
    k_s3<<<NBUCK, 256, 0, stream>>>(bbase, part, gbase);
    k_cscatter<<<NBLK, 256, 0, stream>>>(src, dst, eattr, bbase, bkt);
    k_fine<<<NBUCK, 512, 0, stream>>>(gbase, bkt, packed, rowstart);

    for (int l = 0; l < NLAYERS; ++l) {
        const float* in  = (l == 0) ? x : hprev;
        int Fin          = (l == 0) ? 4 : HC;
        const float* W   = (l == 0) ? W0 : (W13 + (size_t)(l - 1) * HC * HC);
        const float* asr = att_src + l * HC;
        const float* ads = att_dst + l * HC;
        const float* el  = eemb + (size_t)l * ECLS * HC;
        const float* esl = escore + l * ECLS * NHEADS;
        const float* bl  = bias + l * HC;

        k_linear<<<nodeBlocks, 256, 0, stream>>>(in, Fin, W, asr, ads, hcur, ssrc, sdst);
        k_edge<<<nodeBlocks, 256, 0, stream>>>(rowstart, packed, ssrc, sdst, esl,
                                               hcur, el, bl, hprev);
    }

    k_dec<<<decBlocks, 256, 0, stream>>>(hprev, out);
}

// Round 6
// 515.325 us; speedup vs baseline: 5.7385x; 1.2199x over previous
//
#include <hip/hip_runtime.h>
#include <hip/hip_bf16.h>
#include <math.h>

#define N_NODES 100000
#define N_EDGES 1600000
#define HC 64          // H*C
#define NHEADS 2
#define NLAYERS 4
#define ECLS 5
#define NBUCK 196              // ceil(N / 512); bucket = dst >> 9
#define NBLK 256               // coarse pass blocks
#define EPB (N_EDGES / NBLK)   // 6250 edges per coarse block (exact)

// ---------------- CSR build: two-level bucket sort, no global atomics ------

// P1: per-(bucket,block) counts. Block b handles edges [b*EPB, (b+1)*EPB).
__global__ void k_chist(const int* __restrict__ dst, int* __restrict__ bh) {
    __shared__ int lh[NBUCK];
    int tid = threadIdx.x, blk = blockIdx.x;
    for (int i = tid; i < NBUCK; i += 256) lh[i] = 0;
    __syncthreads();
    int s = blk * EPB, e = s + EPB;
    for (int i = s + tid; i < e; i += 256) atomicAdd(&lh[dst[i] >> 9], 1);
    __syncthreads();
    for (int i = tid; i < NBUCK; i += 256) bh[i * 256 + blk] = lh[i];
}

// P2a: per-256-tile exclusive scan of flat bh (bucket-major) -> bbase, tile sums -> part.
__global__ void k_s1(const int* __restrict__ bh, int* __restrict__ bbase,
                     int* __restrict__ part) {
    __shared__ int tmp[256];
    int tid = threadIdx.x;
    int i = blockIdx.x * 256 + tid;
    int v = bh[i];
    tmp[tid] = v;
    __syncthreads();
    for (int off = 1; off < 256; off <<= 1) {
        int t = (tid >= off) ? tmp[tid - off] : 0;
        __syncthreads();
        tmp[tid] += t;
        __syncthreads();
    }
    bbase[i] = tmp[tid] - v;
    if (tid == 255) part[blockIdx.x] = tmp[255];
}

// P2b: exclusive scan of the NBUCK tile sums; total -> gbase[NBUCK].
// Also computes escore[l][c][h] (folded in to save a launch).
__global__ void k_s2(int* __restrict__ part, int* __restrict__ gbase,
                     const float* __restrict__ eemb, const float* __restrict__ att_src,
                     float* __restrict__ escore) {
    __shared__ int tmp[256];
    int tid = threadIdx.x;
    int v = (tid < NBUCK) ? part[tid] : 0;
    tmp[tid] = v;
    __syncthreads();
    for (int off = 1; off < 256; off <<= 1) {
        int t = (tid >= off) ? tmp[tid - off] : 0;
        __syncthreads();
        tmp[tid] += t;
        __syncthreads();
    }
    if (tid < NBUCK) part[tid] = tmp[tid] - v;
    if (tid == 255) gbase[NBUCK] = tmp[255];
    if (tid >= 200 && tid < 200 + NLAYERS * ECLS * NHEADS) {
        int idx = tid - 200;
        int l = idx / (ECLS * NHEADS);
        int r = idx % (ECLS * NHEADS);
        int c = r >> 1;
        int h = r & 1;
        float s = 0.f;
        const float* ev = eemb + l * ECLS * HC + c * HC + h * 32;
        const float* av = att_src + l * HC + h * 32;
        for (int k = 0; k < 32; ++k) s += ev[k] * av[k];
        escore[idx] = s;
    }
}

// P2c: add tile bases -> global exclusive base per (bucket,block); bucket bases -> gbase.
__global__ void k_s3(int* __restrict__ bbase, const int* __restrict__ part,
                     int* __restrict__ gbase) {
    int tid = threadIdx.x;
    int i = blockIdx.x * 256 + tid;
    int v = bbase[i] + part[blockIdx.x];
    bbase[i] = v;
    if (tid == 0) gbase[blockIdx.x] = v;
}

// P3: coarse scatter into bucket-grouped array; LDS atomics only.
__global__ void k_cscatter(const int* __restrict__ src, const int* __restrict__ dst,
                           const int* __restrict__ attr, const int* __restrict__ bbase,
                           int* __restrict__ bkt) {
    __shared__ int cur[NBUCK];
    int tid = threadIdx.x, blk = blockIdx.x;
    for (int i = tid; i < NBUCK; i += 256) cur[i] = bbase[i * 256 + blk];
    __syncthreads();
    int s0 = blk * EPB, e0 = s0 + EPB;
    for (int i = s0 + tid; i < e0; i += 256) {
        int d = dst[i];
        int b = d >> 9;
        int pos = atomicAdd(&cur[b], 1);
        bkt[pos] = src[i] | (attr[i] << 17) | ((d & 511) << 20);
    }
}

// P4: fine sort within each bucket (512 nodes); emits final packed + rowstart.
__global__ void k_fine(const int* __restrict__ gbase, const int* __restrict__ bkt,
                       int* __restrict__ packed, int* __restrict__ rowstart) {
    __shared__ int hist[512];
    __shared__ int cur[512];
    int b = blockIdx.x, tid = threadIdx.x;   // 512 threads
    int base = gbase[b];
    int nb = gbase[b + 1] - base;
    hist[tid] = 0;
    __syncthreads();
    for (int i = tid; i < nb; i += 512)
        atomicAdd(&hist[(bkt[base + i] >> 20) & 0x1FF], 1);
    __syncthreads();
    int v = hist[tid];
    for (int off = 1; off < 512; off <<= 1) {
        int t = (tid >= off) ? hist[tid - off] : 0;
        __syncthreads();
        hist[tid] += t;
        __syncthreads();
    }
    int excl = hist[tid] - v;
    int node = (b << 9) + tid;
    if (node <= N_NODES) rowstart[node] = base + excl;
    cur[tid] = excl;
    __syncthreads();
    for (int i = tid; i < nb; i += 512) {
        int p = bkt[base + i];
        int r = atomicAdd(&cur[(p >> 20) & 0x1FF], 1);
        packed[base + r] = p;
    }
}

// ---------------- per-layer kernels ----------------

// hcur = in @ W ; per-node attention partials ssrc/sdst.
// One wave per node (grid-stride). W column j lives in lane j's registers;
// the row address is wave-uniform (readfirstlane) so row loads scalarize.
// No LDS at all.
template <int FIN>
__global__ void k_linear(const float* __restrict__ in,
                         const float* __restrict__ W,        // [FIN][64]
                         const float* __restrict__ asrc,     // [2][32]
                         const float* __restrict__ adst,     // [2][32]
                         float* __restrict__ hcur,
                         float* __restrict__ ssrc, float* __restrict__ sdst) {
    int j = threadIdx.x & 63;
    int wid = (blockIdx.x * 256 + threadIdx.x) >> 6;
    int nwaves = gridDim.x * 4;

    // W column j -> registers (coalesced across lanes, L2-hot, amortized)
    float w[FIN];
    #pragma unroll
    for (int k = 0; k < FIN; ++k) w[k] = W[k * HC + j];

    int head = j >> 5;
    int c = j & 31;
    float as = asrc[head * 32 + c];
    float ad = adst[head * 32 + c];

    for (int n = wid; n < N_NODES; n += nwaves) {
        int nu = __builtin_amdgcn_readfirstlane(n);
        const float* row = in + (size_t)nu * FIN;
        float acc = 0.f;
        #pragma unroll
        for (int k4 = 0; k4 < FIN / 4; ++k4) {
            float4 r = ((const float4*)row)[k4];
            acc += r.x * w[k4 * 4 + 0];
            acc += r.y * w[k4 * 4 + 1];
            acc += r.z * w[k4 * 4 + 2];
            acc += r.w * w[k4 * 4 + 3];
        }
        hcur[(size_t)nu * HC + j] = acc;

        float ps = acc * as;
        float pd = acc * ad;
        for (int off = 16; off > 0; off >>= 1) {
            ps += __shfl_down(ps, off, 32);
            pd += __shfl_down(pd, off, 32);
        }
        if (c == 0) {
            ssrc[nu * 2 + head] = ps;
            sdst[nu * 2 + head] = pd;
        }
    }
}

// Fused edge pipeline: one wave per dst node.
// Lane layout: sub = lane>>3 (edge slot 0..7), q = lane&7 (channels 8q..8q+7).
// 8 edges in flight per wave; plain softmax (logits are O(1), no max-shift).
__global__ void k_edge(const int* __restrict__ rowstart, const int* __restrict__ packed,
                       const float* __restrict__ ssrc, const float* __restrict__ sdst,
                       const float* __restrict__ escore_l,   // [5][2]
                       const float* __restrict__ hcur,
                       const float* __restrict__ eemb_l,     // [5][64]
                       const float* __restrict__ bias_l,     // [64]
                       float* __restrict__ hnext) {
    int n = blockIdx.x * 4 + (threadIdx.x >> 6);
    if (n >= N_NODES) return;
    int lane = threadIdx.x & 63;
    int sub = lane >> 3;       // edge slot 0..7
    int q   = lane & 7;        // channel octet: channels 8q..8q+7
    int h   = q >> 2;          // head (q<4 -> ch<32 -> head0)

    int beg = rowstart[n];
    int end = rowstart[n + 1];
    float sd = sdst[n * 2 + h];

    float4 a0 = make_float4(0.f, 0.f, 0.f, 0.f);
    float4 a1 = make_float4(0.f, 0.f, 0.f, 0.f);
    float ssum = 0.f;
    for (int i = beg + sub; i < end; i += 8) {
        int p = packed[i];
        int s = p & 0x1FFFF;
        int a = (p >> 17) & 7;
        float lg = sd + ssrc[s * 2 + h] + escore_l[a * 2 + h];
        lg = lg >= 0.f ? lg : 0.2f * lg;
        float w = __expf(lg);
        const float4* hp = (const float4*)(hcur + (size_t)s * HC + q * 8);
        const float4* ep = (const float4*)(eemb_l + a * HC + q * 8);
        float4 h0 = hp[0], h1 = hp[1];
        float4 e0 = ep[0], e1 = ep[1];
        a0.x += w * (h0.x + e0.x);
        a0.y += w * (h0.y + e0.y);
        a0.z += w * (h0.z + e0.z);
        a0.w += w * (h0.w + e0.w);
        a1.x += w * (h1.x + e1.x);
        a1.y += w * (h1.y + e1.y);
        a1.z += w * (h1.z + e1.z);
        a1.w += w * (h1.w + e1.w);
        ssum += w;
    }
    // reduce the 8 edge slots (lanes differing in bits 3,4,5; q/head preserved)
    for (int off = 8; off < 64; off <<= 1) {
        a0.x += __shfl_xor(a0.x, off, 64);
        a0.y += __shfl_xor(a0.y, off, 64);
        a0.z += __shfl_xor(a0.z, off, 64);
        a0.w += __shfl_xor(a0.w, off, 64);
        a1.x += __shfl_xor(a1.x, off, 64);
        a1.y += __shfl_xor(a1.y, off, 64);
        a1.z += __shfl_xor(a1.z, off, 64);
        a1.w += __shfl_xor(a1.w, off, 64);
        ssum  += __shfl_xor(ssum,  off, 64);
    }
    if (sub == 0) {
        float inv = 1.f / (ssum + 1e-16f);
        const float4* bp = (const float4*)(bias_l + q * 8);
        float4 b0 = bp[0], b1 = bp[1];
        float4 o0, o1;
        o0.x = a0.x * inv + b0.x;  o0.x = o0.x > 0.f ? o0.x : expm1f(o0.x);
        o0.y = a0.y * inv + b0.y;  o0.y = o0.y > 0.f ? o0.y : expm1f(o0.y);
        o0.z = a0.z * inv + b0.z;  o0.z = o0.z > 0.f ? o0.z : expm1f(o0.z);
        o0.w = a0.w * inv + b0.w;  o0.w = o0.w > 0.f ? o0.w : expm1f(o0.w);
        o1.x = a1.x * inv + b1.x;  o1.x = o1.x > 0.f ? o1.x : expm1f(o1.x);
        o1.y = a1.y * inv + b1.y;  o1.y = o1.y > 0.f ? o1.y : expm1f(o1.y);
        o1.z = a1.z * inv + b1.z;  o1.z = o1.z > 0.f ? o1.z : expm1f(o1.z);
        o1.w = a1.w * inv + b1.w;  o1.w = o1.w > 0.f ? o1.w : expm1f(o1.w);
        float4* op = (float4*)(hnext + (size_t)n * HC + q * 8);
        op[0] = o0;
        op[1] = o1;
    }
}

// Decoder: out[k] = dot(h[4k], h[4k+1]) over 64 channels. 4 pairs/block.
__global__ void k_dec(const float* __restrict__ h, float* __restrict__ out) {
    int k = blockIdx.x * 4 + (threadIdx.x >> 6);
    int j = threadIdx.x & 63;
    if (k >= N_NODES / 4) return;
    float u = h[(size_t)(4 * k) * HC + j];
    float v = h[(size_t)(4 * k + 1) * HC + j];
    float p = u * v;
    for (int off = 32; off > 0; off >>= 1) p += __shfl_down(p, off, 64);
    if (j == 0) out[k] = p;
}

// ---------------- launch ----------------
extern "C" void kernel_launch(void* const* d_in, const int* in_sizes, int n_in,
                              void* d_out, int out_size, void* d_ws, size_t ws_size,
                              hipStream_t stream) {
    const float* x       = (const float*)d_in[0];   // [N,4]
    const float* W0      = (const float*)d_in[1];   // [4,64]
    const float* W13     = (const float*)d_in[2];   // [3,64,64]
    const float* eemb    = (const float*)d_in[3];   // [4,5,64]
    const float* att_src = (const float*)d_in[4];   // [4,2,32]
    const float* att_dst = (const float*)d_in[5];   // [4,2,32]
    const float* bias    = (const float*)d_in[6];   // [4,64]
    const int*   eidx    = (const int*)d_in[7];     // [2,E]
    const int*   eattr   = (const int*)d_in[8];     // [E]
    float* out = (float*)d_out;

    const int* src = eidx;
    const int* dst = eidx + N_EDGES;

    // workspace layout
    char* wsb = (char*)d_ws;
    size_t off = 0;
    auto alloc = [&](size_t bytes) { char* p = wsb + off; off += (bytes + 255) & ~(size_t)255; return p; };
    float* hprev    = (float*)alloc((size_t)N_NODES * HC * 4);
    float* hcur     = (float*)alloc((size_t)N_NODES * HC * 4);
    float* ssrc     = (float*)alloc((size_t)N_NODES * 2 * 4);
    float* sdst     = (float*)alloc((size_t)N_NODES * 2 * 4);
    float* escore   = (float*)alloc(NLAYERS * ECLS * NHEADS * 4);
    int*   bh       = (int*)alloc((size_t)NBUCK * 256 * 4);
    int*   bbase    = (int*)alloc((size_t)NBUCK * 256 * 4);
    int*   part     = (int*)alloc(256 * 4);
    int*   gbase    = (int*)alloc((NBUCK + 1) * 4);
    int*   rowstart = (int*)alloc(((size_t)N_NODES + 1) * 4);
    int*   bkt      = (int*)alloc((size_t)N_EDGES * 4);
    int*   packed   = (int*)alloc((size_t)N_EDGES * 4);

    const int nodeBlocks = (N_NODES + 3) / 4;
    const int linBlocks  = 2048;                     // grid-stride waves
    const int decBlocks  = (N_NODES / 4 + 3) / 4;

    // ---- CSR build: bucket sort, no global atomics ----
    k_chist<<<NBLK, 256, 0, stream>>>(dst, bh);
    k_s1<<<NBUCK, 256, 0, stream>>>(bh, bbase, part);
    k_s2<<<1, 256, 0, stream>>>(part, gbase, eemb, att_src, escore);
    k_s3<<<NBUCK, 256, 0, stream>>>(bbase, part, gbase);
    k_cscatter<<<NBLK, 256, 0, stream>>>(src, dst, eattr, bbase, bkt);
    k_fine<<<NBUCK, 512, 0, stream>>>(gbase, bkt, packed, rowstart);

    for (int l = 0; l < NLAYERS; ++l) {
        const float* asr = att_src + l * HC;
        const float* ads = att_dst + l * HC;
        const float* el  = eemb + (size_t)l * ECLS * HC;
        const float* esl = escore + l * ECLS * NHEADS;
        const float* bl  = bias + l * HC;

        if (l == 0)
            k_linear<4><<<linBlocks, 256, 0, stream>>>(x, W0, asr, ads, hcur, ssrc, sdst);
        else
            k_linear<64><<<linBlocks, 256, 0, stream>>>(hprev, W13 + (size_t)(l - 1) * HC * HC,
                                                        asr, ads, hcur, ssrc, sdst);
        k_edge<<<nodeBlocks, 256, 0, stream>>>(rowstart, packed, ssrc, sdst, esl,
                                               hcur, el, bl, hprev);
    }

    k_dec<<<decBlocks, 256, 0, stream>>>(hprev, out);
}

// Round 8
// 482.198 us; speedup vs baseline: 6.1327x; 1.0687x over previous
//
#include <hip/hip_runtime.h>
#include <hip/hip_bf16.h>
#include <math.h>

#define N_NODES 100000
#define N_EDGES 1600000
#define HC 64          // H*C
#define NHEADS 2
#define NLAYERS 4
#define ECLS 5
#define NBUCK 196              // ceil(N / 512); bucket = dst >> 9
#define NBLK 256               // coarse pass blocks
#define EPB (N_EDGES / NBLK)   // 6250 edges per coarse block (exact)

// bf16 (stored as ushort) -> f32
__device__ inline float bf_lo(unsigned int u) { return __uint_as_float(u << 16); }
__device__ inline float bf_hi(unsigned int u) { return __uint_as_float(u & 0xffff0000u); }
// f32 -> bf16 bits, round-to-nearest-even
__device__ inline unsigned short f2bf(float f) {
    unsigned int u = __float_as_uint(f);
    u += 0x7FFFu + ((u >> 16) & 1u);
    return (unsigned short)(u >> 16);
}

// ---------------- CSR build: two-level bucket sort, no global atomics ------

// P1: per-(bucket,block) counts. Block b handles edges [b*EPB, (b+1)*EPB).
__global__ void k_chist(const int* __restrict__ dst, int* __restrict__ bh) {
    __shared__ int lh[NBUCK];
    int tid = threadIdx.x, blk = blockIdx.x;
    for (int i = tid; i < NBUCK; i += 256) lh[i] = 0;
    __syncthreads();
    int s = blk * EPB, e = s + EPB;
    for (int i = s + tid; i < e; i += 256) atomicAdd(&lh[dst[i] >> 9], 1);
    __syncthreads();
    for (int i = tid; i < NBUCK; i += 256) bh[i * 256 + blk] = lh[i];
}

// P2a: per-256-tile exclusive scan of flat bh (bucket-major) -> bbase, tile sums -> part.
__global__ void k_s1(const int* __restrict__ bh, int* __restrict__ bbase,
                     int* __restrict__ part) {
    __shared__ int tmp[256];
    int tid = threadIdx.x;
    int i = blockIdx.x * 256 + tid;
    int v = bh[i];
    tmp[tid] = v;
    __syncthreads();
    for (int off = 1; off < 256; off <<= 1) {
        int t = (tid >= off) ? tmp[tid - off] : 0;
        __syncthreads();
        tmp[tid] += t;
        __syncthreads();
    }
    bbase[i] = tmp[tid] - v;
    if (tid == 255) part[blockIdx.x] = tmp[255];
}

// P2b: exclusive scan of the NBUCK tile sums; total -> gbase[NBUCK].
// Also computes escore[l][c][h] (folded in to save a launch).
__global__ void k_s2(int* __restrict__ part, int* __restrict__ gbase,
                     const float* __restrict__ eemb, const float* __restrict__ att_src,
                     float* __restrict__ escore) {
    __shared__ int tmp[256];
    int tid = threadIdx.x;
    int v = (tid < NBUCK) ? part[tid] : 0;
    tmp[tid] = v;
    __syncthreads();
    for (int off = 1; off < 256; off <<= 1) {
        int t = (tid >= off) ? tmp[tid - off] : 0;
        __syncthreads();
        tmp[tid] += t;
        __syncthreads();
    }
    if (tid < NBUCK) part[tid] = tmp[tid] - v;
    if (tid == 255) gbase[NBUCK] = tmp[255];
    if (tid >= 200 && tid < 200 + NLAYERS * ECLS * NHEADS) {
        int idx = tid - 200;
        int l = idx / (ECLS * NHEADS);
        int r = idx % (ECLS * NHEADS);
        int c = r >> 1;
        int h = r & 1;
        float s = 0.f;
        const float* ev = eemb + l * ECLS * HC + c * HC + h * 32;
        const float* av = att_src + l * HC + h * 32;
        for (int k = 0; k < 32; ++k) s += ev[k] * av[k];
        escore[idx] = s;
    }
}

// P2c: add tile bases -> global exclusive base per (bucket,block); bucket bases -> gbase.
__global__ void k_s3(int* __restrict__ bbase, const int* __restrict__ part,
                     int* __restrict__ gbase) {
    int tid = threadIdx.x;
    int i = blockIdx.x * 256 + tid;
    int v = bbase[i] + part[blockIdx.x];
    bbase[i] = v;
    if (tid == 0) gbase[blockIdx.x] = v;
}

// P3: coarse scatter into bucket-grouped array; LDS atomics only.
__global__ void k_cscatter(const int* __restrict__ src, const int* __restrict__ dst,
                           const int* __restrict__ attr, const int* __restrict__ bbase,
                           int* __restrict__ bkt) {
    __shared__ int cur[NBUCK];
    int tid = threadIdx.x, blk = blockIdx.x;
    for (int i = tid; i < NBUCK; i += 256) cur[i] = bbase[i * 256 + blk];
    __syncthreads();
    int s0 = blk * EPB, e0 = s0 + EPB;
    for (int i = s0 + tid; i < e0; i += 256) {
        int d = dst[i];
        int b = d >> 9;
        int pos = atomicAdd(&cur[b], 1);
        bkt[pos] = src[i] | (attr[i] << 17) | ((d & 511) << 20);
    }
}

// P4: fine sort within each bucket (512 nodes); emits final packed + rowstart.
__global__ void k_fine(const int* __restrict__ gbase, const int* __restrict__ bkt,
                       int* __restrict__ packed, int* __restrict__ rowstart) {
    __shared__ int hist[512];
    __shared__ int cur[512];
    int b = blockIdx.x, tid = threadIdx.x;   // 512 threads
    int base = gbase[b];
    int nb = gbase[b + 1] - base;
    hist[tid] = 0;
    __syncthreads();
    for (int i = tid; i < nb; i += 512)
        atomicAdd(&hist[(bkt[base + i] >> 20) & 0x1FF], 1);
    __syncthreads();
    int v = hist[tid];
    for (int off = 1; off < 512; off <<= 1) {
        int t = (tid >= off) ? hist[tid - off] : 0;
        __syncthreads();
        hist[tid] += t;
        __syncthreads();
    }
    int excl = hist[tid] - v;
    int node = (b << 9) + tid;
    if (node <= N_NODES) rowstart[node] = base + excl;
    cur[tid] = excl;
    __syncthreads();
    for (int i = tid; i < nb; i += 512) {
        int p = bkt[base + i];
        int r = atomicAdd(&cur[(p >> 20) & 0x1FF], 1);
        packed[base + r] = p;
    }
}

// ---------------- per-layer kernels ----------------

// hcur(bf16) = in @ W ; per-node attention partials ssrc/sdst (fp32).
// One wave per node (grid-stride). W column j lives in lane j's registers;
// the row address is wave-uniform (readfirstlane) so row loads scalarize.
template <int FIN>
__global__ void k_linear(const float* __restrict__ in,
                         const float* __restrict__ W,        // [FIN][64]
                         const float* __restrict__ asrc,     // [2][32]
                         const float* __restrict__ adst,     // [2][32]
                         unsigned short* __restrict__ hcurb, // [N][64] bf16
                         float* __restrict__ ssrc, float* __restrict__ sdst) {
    int j = threadIdx.x & 63;
    int wid = (blockIdx.x * 256 + threadIdx.x) >> 6;
    int nwaves = gridDim.x * 4;

    float w[FIN];
    #pragma unroll
    for (int k = 0; k < FIN; ++k) w[k] = W[k * HC + j];

    int head = j >> 5;
    int c = j & 31;
    float as = asrc[head * 32 + c];
    float ad = adst[head * 32 + c];

    for (int n = wid; n < N_NODES; n += nwaves) {
        int nu = __builtin_amdgcn_readfirstlane(n);
        const float* row = in + (size_t)nu * FIN;
        float acc = 0.f;
        #pragma unroll
        for (int k4 = 0; k4 < FIN / 4; ++k4) {
            float4 r = ((const float4*)row)[k4];
            acc += r.x * w[k4 * 4 + 0];
            acc += r.y * w[k4 * 4 + 1];
            acc += r.z * w[k4 * 4 + 2];
            acc += r.w * w[k4 * 4 + 3];
        }
        hcurb[(size_t)nu * HC + j] = f2bf(acc);

        float ps = acc * as;
        float pd = acc * ad;
        for (int off = 16; off > 0; off >>= 1) {
            ps += __shfl_down(ps, off, 32);
            pd += __shfl_down(pd, off, 32);
        }
        if (c == 0) {
            ssrc[nu * 2 + head] = ps;
            sdst[nu * 2 + head] = pd;
        }
    }
}

// Fused edge pipeline: one wave per dst node.
// Lane layout: sub = lane>>3 (edge slot 0..7), q = lane&7 (channels 8q..8q+7).
// 8 edges in flight; hcur gathered as bf16 (one dwordx4 per lane per edge);
// accumulation fp32; plain softmax (logits are O(1), no max-shift).
__global__ void k_edge(const int* __restrict__ rowstart, const int* __restrict__ packed,
                       const float* __restrict__ ssrc, const float* __restrict__ sdst,
                       const float* __restrict__ escore_l,   // [5][2]
                       const unsigned short* __restrict__ hcurb, // [N][64] bf16
                       const float* __restrict__ eemb_l,     // [5][64]
                       const float* __restrict__ bias_l,     // [64]
                       float* __restrict__ hnext) {
    int n = blockIdx.x * 4 + (threadIdx.x >> 6);
    if (n >= N_NODES) return;
    int lane = threadIdx.x & 63;
    int sub = lane >> 3;       // edge slot 0..7
    int q   = lane & 7;        // channel octet: channels 8q..8q+7
    int h   = q >> 2;          // head (q<4 -> ch<32 -> head0)

    int beg = rowstart[n];
    int end = rowstart[n + 1];
    float sd = sdst[n * 2 + h];

    float4 a0 = make_float4(0.f, 0.f, 0.f, 0.f);
    float4 a1 = make_float4(0.f, 0.f, 0.f, 0.f);
    float ssum = 0.f;
    for (int i = beg + sub; i < end; i += 8) {
        int p = packed[i];
        int s = p & 0x1FFFF;
        int a = (p >> 17) & 7;
        float lg = sd + ssrc[s * 2 + h] + escore_l[a * 2 + h];
        lg = lg >= 0.f ? lg : 0.2f * lg;
        float w = __expf(lg);
        uint4 hv = *(const uint4*)(hcurb + (size_t)s * HC + q * 8);
        const float4* ep = (const float4*)(eemb_l + a * HC + q * 8);
        float4 e0 = ep[0], e1 = ep[1];
        a0.x += w * (bf_lo(hv.x) + e0.x);
        a0.y += w * (bf_hi(hv.x) + e0.y);
        a0.z += w * (bf_lo(hv.y) + e0.z);
        a0.w += w * (bf_hi(hv.y) + e0.w);
        a1.x += w * (bf_lo(hv.z) + e1.x);
        a1.y += w * (bf_hi(hv.z) + e1.y);
        a1.z += w * (bf_lo(hv.w) + e1.z);
        a1.w += w * (bf_hi(hv.w) + e1.w);
        ssum += w;
    }
    // reduce the 8 edge slots (lanes differing in bits 3,4,5; q/head preserved)
    for (int off = 8; off < 64; off <<= 1) {
        a0.x += __shfl_xor(a0.x, off, 64);
        a0.y += __shfl_xor(a0.y, off, 64);
        a0.z += __shfl_xor(a0.z, off, 64);
        a0.w += __shfl_xor(a0.w, off, 64);
        a1.x += __shfl_xor(a1.x, off, 64);
        a1.y += __shfl_xor(a1.y, off, 64);
        a1.z += __shfl_xor(a1.z, off, 64);
        a1.w += __shfl_xor(a1.w, off, 64);
        ssum  += __shfl_xor(ssum,  off, 64);
    }
    if (sub == 0) {
        float inv = 1.f / (ssum + 1e-16f);
        const float4* bp = (const float4*)(bias_l + q * 8);
        float4 b0 = bp[0], b1 = bp[1];
        float4 o0, o1;
        o0.x = a0.x * inv + b0.x;  o0.x = o0.x > 0.f ? o0.x : expm1f(o0.x);
        o0.y = a0.y * inv + b0.y;  o0.y = o0.y > 0.f ? o0.y : expm1f(o0.y);
        o0.z = a0.z * inv + b0.z;  o0.z = o0.z > 0.f ? o0.z : expm1f(o0.z);
        o0.w = a0.w * inv + b0.w;  o0.w = o0.w > 0.f ? o0.w : expm1f(o0.w);
        o1.x = a1.x * inv + b1.x;  o1.x = o1.x > 0.f ? o1.x : expm1f(o1.x);
        o1.y = a1.y * inv + b1.y;  o1.y = o1.y > 0.f ? o1.y : expm1f(o1.y);
        o1.z = a1.z * inv + b1.z;  o1.z = o1.z > 0.f ? o1.z : expm1f(o1.z);
        o1.w = a1.w * inv + b1.w;  o1.w = o1.w > 0.f ? o1.w : expm1f(o1.w);
        float4* op = (float4*)(hnext + (size_t)n * HC + q * 8);
        op[0] = o0;
        op[1] = o1;
    }
}

// Decoder: out[k] = dot(h[4k], h[4k+1]) over 64 channels. 4 pairs/block.
__global__ void k_dec(const float* __restrict__ h, float* __restrict__ out) {
    int k = blockIdx.x * 4 + (threadIdx.x >> 6);
    int j = threadIdx.x & 63;
    if (k >= N_NODES / 4) return;
    float u = h[(size_t)(4 * k) * HC + j];
    float v = h[(size_t)(4 * k + 1) * HC + j];
    float p = u * v;
    for (int off = 32; off > 0; off >>= 1) p += __shfl_down(p, off, 64);
    if (j == 0) out[k] = p;
}

// ---------------- launch ----------------
extern "C" void kernel_launch(void* const* d_in, const int* in_sizes, int n_in,
                              void* d_out, int out_size, void* d_ws, size_t ws_size,
                              hipStream_t stream) {
    const float* x       = (const float*)d_in[0];   // [N,4]
    const float* W0      = (const float*)d_in[1];   // [4,64]
    const float* W13     = (const float*)d_in[2];   // [3,64,64]
    const float* eemb    = (const float*)d_in[3];   // [4,5,64]
    const float* att_src = (const float*)d_in[4];   // [4,2,32]
    const float* att_dst = (const float*)d_in[5];   // [4,2,32]
    const float* bias    = (const float*)d_in[6];   // [4,64]
    const int*   eidx    = (const int*)d_in[7];     // [2,E]
    const int*   eattr   = (const int*)d_in[8];     // [E]
    float* out = (float*)d_out;

    const int* src = eidx;
    const int* dst = eidx + N_EDGES;

    // workspace layout
    char* wsb = (char*)d_ws;
    size_t off = 0;
    auto alloc = [&](size_t bytes) { char* p = wsb + off; off += (bytes + 255) & ~(size_t)255; return p; };
    float*          hprev    = (float*)alloc((size_t)N_NODES * HC * 4);
    unsigned short* hcurb    = (unsigned short*)alloc((size_t)N_NODES * HC * 2);
    float*          ssrc     = (float*)alloc((size_t)N_NODES * 2 * 4);
    float*          sdst     = (float*)alloc((size_t)N_NODES * 2 * 4);
    float*          escore   = (float*)alloc(NLAYERS * ECLS * NHEADS * 4);
    int*            bh       = (int*)alloc((size_t)NBUCK * 256 * 4);
    int*            bbase    = (int*)alloc((size_t)NBUCK * 256 * 4);
    int*            part     = (int*)alloc(256 * 4);
    int*            gbase    = (int*)alloc((NBUCK + 1) * 4);
    int*            rowstart = (int*)alloc(((size_t)N_NODES + 1) * 4);
    int*            bkt      = (int*)alloc((size_t)N_EDGES * 4);
    int*            packed   = (int*)alloc((size_t)N_EDGES * 4);

    const int nodeBlocks = (N_NODES + 3) / 4;
    const int linBlocks  = 2048;                     // grid-stride waves
    const int decBlocks  = (N_NODES / 4 + 3) / 4;

    // ---- CSR build: bucket sort, no global atomics ----
    k_chist<<<NBLK, 256, 0, stream>>>(dst, bh);
    k_s1<<<NBUCK, 256, 0, stream>>>(bh, bbase, part);
    k_s2<<<1, 256, 0, stream>>>(part, gbase, eemb, att_src, escore);
    k_s3<<<NBUCK, 256, 0, stream>>>(bbase, part, gbase);
    k_cscatter<<<NBLK, 256, 0, stream>>>(src, dst, eattr, bbase, bkt);
    k_fine<<<NBUCK, 512, 0, stream>>>(gbase, bkt, packed, rowstart);

    for (int l = 0; l < NLAYERS; ++l) {
        const float* asr = att_src + l * HC;
        const float* ads = att_dst + l * HC;
        const float* el  = eemb + (size_t)l * ECLS * HC;
        const float* esl = escore + l * ECLS * NHEADS;
        const float* bl  = bias + l * HC;

        if (l == 0)
            k_linear<4><<<linBlocks, 256, 0, stream>>>(x, W0, asr, ads, hcurb, ssrc, sdst);
        else
            k_linear<64><<<linBlocks, 256, 0, stream>>>(hprev, W13 + (size_t)(l - 1) * HC * HC,
                                                        asr, ads, hcurb, ssrc, sdst);
        k_edge<<<nodeBlocks, 256, 0, stream>>>(rowstart, packed, ssrc, sdst, esl,
                                               hcurb, el, bl, hprev);
    }

    k_dec<<<decBlocks, 256, 0, stream>>>(hprev, out);
}

// Round 9
// 434.953 us; speedup vs baseline: 6.7989x; 1.1086x over previous
//
#include <hip/hip_runtime.h>
#include <hip/hip_bf16.h>
#include <math.h>

#define N_NODES 100000
#define N_EDGES 1600000
#define HC 64          // H*C
#define NHEADS 2
#define NLAYERS 4
#define ECLS 5
#define NBUCK 196              // ceil(N / 512); bucket = dst >> 9
#define NBLK 256               // coarse pass blocks
#define EPB (N_EDGES / NBLK)   // 6250 edges per coarse block (exact)

// bf16 (stored as ushort) -> f32
__device__ inline float bf_lo(unsigned int u) { return __uint_as_float(u << 16); }
__device__ inline float bf_hi(unsigned int u) { return __uint_as_float(u & 0xffff0000u); }
// f32 -> bf16 bits, round-to-nearest-even
__device__ inline unsigned short f2bf(float f) {
    unsigned int u = __float_as_uint(f);
    u += 0x7FFFu + ((u >> 16) & 1u);
    return (unsigned short)(u >> 16);
}

// ---------------- CSR build: two-level bucket sort, no global atomics ------

// P1: per-(bucket,block) counts. Block b handles edges [b*EPB, (b+1)*EPB).
__global__ void k_chist(const int* __restrict__ dst, int* __restrict__ bh) {
    __shared__ int lh[NBUCK];
    int tid = threadIdx.x, blk = blockIdx.x;
    for (int i = tid; i < NBUCK; i += 256) lh[i] = 0;
    __syncthreads();
    int s = blk * EPB, e = s + EPB;
    for (int i = s + tid; i < e; i += 256) atomicAdd(&lh[dst[i] >> 9], 1);
    __syncthreads();
    for (int i = tid; i < NBUCK; i += 256) bh[i * 256 + blk] = lh[i];
}

// P2a: per-bucket (256-tile) exclusive scan of bh -> bbase, bucket sums -> part.
__global__ void k_s1(const int* __restrict__ bh, int* __restrict__ bbase,
                     int* __restrict__ part) {
    __shared__ int tmp[256];
    int tid = threadIdx.x;
    int i = blockIdx.x * 256 + tid;
    int v = bh[i];
    tmp[tid] = v;
    __syncthreads();
    for (int off = 1; off < 256; off <<= 1) {
        int t = (tid >= off) ? tmp[tid - off] : 0;
        __syncthreads();
        tmp[tid] += t;
        __syncthreads();
    }
    bbase[i] = tmp[tid] - v;
    if (tid == 255) part[blockIdx.x] = tmp[255];
}

// P2b: exclusive scan of the NBUCK bucket sums in-place (part becomes bucket base).
// Also computes escore[l][c][h] (folded in to save a launch).
__global__ void k_s2(int* __restrict__ part,
                     const float* __restrict__ eemb, const float* __restrict__ att_src,
                     float* __restrict__ escore) {
    __shared__ int tmp[256];
    int tid = threadIdx.x;
    int v = (tid < NBUCK) ? part[tid] : 0;
    tmp[tid] = v;
    __syncthreads();
    for (int off = 1; off < 256; off <<= 1) {
        int t = (tid >= off) ? tmp[tid - off] : 0;
        __syncthreads();
        tmp[tid] += t;
        __syncthreads();
    }
    if (tid < NBUCK) part[tid] = tmp[tid] - v;
    if (tid >= 200 && tid < 200 + NLAYERS * ECLS * NHEADS) {
        int idx = tid - 200;
        int l = idx / (ECLS * NHEADS);
        int r = idx % (ECLS * NHEADS);
        int c = r >> 1;
        int h = r & 1;
        float s = 0.f;
        const float* ev = eemb + l * ECLS * HC + c * HC + h * 32;
        const float* av = att_src + l * HC + h * 32;
        for (int k = 0; k < 32; ++k) s += ev[k] * av[k];
        escore[idx] = s;
    }
}

// P3: coarse scatter into bucket-grouped array; LDS atomics only.
// Global base = bbase[bucket*256+blk] (within-bucket) + part[bucket] (bucket base).
__global__ void k_cscatter(const int* __restrict__ src, const int* __restrict__ dst,
                           const int* __restrict__ attr, const int* __restrict__ bbase,
                           const int* __restrict__ part, int* __restrict__ bkt) {
    __shared__ int cur[NBUCK];
    int tid = threadIdx.x, blk = blockIdx.x;
    for (int i = tid; i < NBUCK; i += 256) cur[i] = bbase[i * 256 + blk] + part[i];
    __syncthreads();
    int s0 = blk * EPB, e0 = s0 + EPB;
    for (int i = s0 + tid; i < e0; i += 256) {
        int d = dst[i];
        int b = d >> 9;
        int pos = atomicAdd(&cur[b], 1);
        bkt[pos] = src[i] | (attr[i] << 17) | ((d & 511) << 20);
    }
}

// P4: fine sort within each bucket (512 nodes); emits final packed + rowstart.
__global__ void k_fine(const int* __restrict__ part, const int* __restrict__ bkt,
                       int* __restrict__ packed, int* __restrict__ rowstart) {
    __shared__ int hist[512];
    __shared__ int cur[512];
    int b = blockIdx.x, tid = threadIdx.x;   // 512 threads
    int base = part[b];
    int bend = (b + 1 < NBUCK) ? part[b + 1] : N_EDGES;
    int nb = bend - base;
    hist[tid] = 0;
    __syncthreads();
    for (int i = tid; i < nb; i += 512)
        atomicAdd(&hist[(bkt[base + i] >> 20) & 0x1FF], 1);
    __syncthreads();
    int v = hist[tid];
    for (int off = 1; off < 512; off <<= 1) {
        int t = (tid >= off) ? hist[tid - off] : 0;
        __syncthreads();
        hist[tid] += t;
        __syncthreads();
    }
    int excl = hist[tid] - v;
    int node = (b << 9) + tid;
    if (node <= N_NODES) rowstart[node] = base + excl;
    cur[tid] = excl;
    __syncthreads();
    for (int i = tid; i < nb; i += 512) {
        int p = bkt[base + i];
        int r = atomicAdd(&cur[(p >> 20) & 0x1FF], 1);
        packed[base + r] = p;
    }
}

// ---------------- per-layer kernels ----------------

// hcur(bf16) = in @ W ; per-node attention partials ssrc/sdst (fp32).
// One wave per node (grid-stride). W column j lives in lane j's registers;
// the row address is wave-uniform (readfirstlane) so row loads scalarize.
template <int FIN>
__global__ void k_linear(const float* __restrict__ in,
                         const float* __restrict__ W,        // [FIN][64]
                         const float* __restrict__ asrc,     // [2][32]
                         const float* __restrict__ adst,     // [2][32]
                         unsigned short* __restrict__ hcurb, // [N][64] bf16
                         float* __restrict__ ssrc, float* __restrict__ sdst) {
    int j = threadIdx.x & 63;
    int wid = (blockIdx.x * 256 + threadIdx.x) >> 6;
    int nwaves = gridDim.x * 4;

    float w[FIN];
    #pragma unroll
    for (int k = 0; k < FIN; ++k) w[k] = W[k * HC + j];

    int head = j >> 5;
    int c = j & 31;
    float as = asrc[head * 32 + c];
    float ad = adst[head * 32 + c];

    for (int n = wid; n < N_NODES; n += nwaves) {
        int nu = __builtin_amdgcn_readfirstlane(n);
        const float* row = in + (size_t)nu * FIN;
        float acc = 0.f;
        #pragma unroll
        for (int k4 = 0; k4 < FIN / 4; ++k4) {
            float4 r = ((const float4*)row)[k4];
            acc += r.x * w[k4 * 4 + 0];
            acc += r.y * w[k4 * 4 + 1];
            acc += r.z * w[k4 * 4 + 2];
            acc += r.w * w[k4 * 4 + 3];
        }
        hcurb[(size_t)nu * HC + j] = f2bf(acc);

        float ps = acc * as;
        float pd = acc * ad;
        for (int off = 16; off > 0; off >>= 1) {
            ps += __shfl_down(ps, off, 32);
            pd += __shfl_down(pd, off, 32);
        }
        if (c == 0) {
            ssrc[nu * 2 + head] = ps;
            sdst[nu * 2 + head] = pd;
        }
    }
}

// Fused edge pipeline: one wave per dst node; block = 4 nodes.
// Lane layout: sub = lane>>3 (edge slot 0..7), q = lane&7 (channels 8q..8q+7).
// Epilogue: LDS bounce so all 64 lanes do 1-channel ELU (elu via expf-1).
// LAST: fuse the MF decoder — out[b] = dot(h[4b], h[4b+1]); skip hnext store.
template <bool LAST>
__global__ void k_edge(const int* __restrict__ rowstart, const int* __restrict__ packed,
                       const float* __restrict__ ssrc, const float* __restrict__ sdst,
                       const float* __restrict__ escore_l,   // [5][2]
                       const unsigned short* __restrict__ hcurb, // [N][64] bf16
                       const float* __restrict__ eemb_l,     // [5][64]
                       const float* __restrict__ bias_l,     // [64]
                       float* __restrict__ hnext, float* __restrict__ out) {
    __shared__ float lbuf[4][64];
    __shared__ float obuf[2][64];
    int w = threadIdx.x >> 6;
    int n = blockIdx.x * 4 + w;                 // always < N (grid = N/4 exact)
    int lane = threadIdx.x & 63;
    int sub = lane >> 3;       // edge slot 0..7
    int q   = lane & 7;        // channel octet: channels 8q..8q+7
    int h   = q >> 2;          // head (q<4 -> ch<32 -> head0)

    int beg = rowstart[n];
    int end = rowstart[n + 1];
    float sd = sdst[n * 2 + h];

    float4 a0 = make_float4(0.f, 0.f, 0.f, 0.f);
    float4 a1 = make_float4(0.f, 0.f, 0.f, 0.f);
    float ssum = 0.f;
    for (int i = beg + sub; i < end; i += 8) {
        int p = packed[i];
        int s = p & 0x1FFFF;
        int a = (p >> 17) & 7;
        float lg = sd + ssrc[s * 2 + h] + escore_l[a * 2 + h];
        lg = lg >= 0.f ? lg : 0.2f * lg;
        float wt = __expf(lg);
        uint4 hv = *(const uint4*)(hcurb + (size_t)s * HC + q * 8);
        const float4* ep = (const float4*)(eemb_l + a * HC + q * 8);
        float4 e0 = ep[0], e1 = ep[1];
        a0.x += wt * (bf_lo(hv.x) + e0.x);
        a0.y += wt * (bf_hi(hv.x) + e0.y);
        a0.z += wt * (bf_lo(hv.y) + e0.z);
        a0.w += wt * (bf_hi(hv.y) + e0.w);
        a1.x += wt * (bf_lo(hv.z) + e1.x);
        a1.y += wt * (bf_hi(hv.z) + e1.y);
        a1.z += wt * (bf_lo(hv.w) + e1.z);
        a1.w += wt * (bf_hi(hv.w) + e1.w);
        ssum += wt;
    }
    // reduce the 8 edge slots (lanes differing in bits 3,4,5; q/head preserved)
    for (int off = 8; off < 64; off <<= 1) {
        a0.x += __shfl_xor(a0.x, off, 64);
        a0.y += __shfl_xor(a0.y, off, 64);
        a0.z += __shfl_xor(a0.z, off, 64);
        a0.w += __shfl_xor(a0.w, off, 64);
        a1.x += __shfl_xor(a1.x, off, 64);
        a1.y += __shfl_xor(a1.y, off, 64);
        a1.z += __shfl_xor(a1.z, off, 64);
        a1.w += __shfl_xor(a1.w, off, 64);
        ssum  += __shfl_xor(ssum,  off, 64);
    }
    float inv = 1.f / (ssum + 1e-16f);          // ssum broadcast to all lanes
    if (sub == 0) {
        ((float4*)&lbuf[w][q * 8])[0] = a0;
        ((float4*)&lbuf[w][q * 8])[1] = a1;
    }
    __builtin_amdgcn_wave_barrier();            // DS ops are in-order per wave
    float v = lbuf[w][lane] * inv + bias_l[lane];
    float o = v > 0.f ? v : (__expf(v) - 1.f);  // elu; expf-1 ~= expm1 well within tol
    if (!LAST) {
        hnext[(size_t)n * HC + lane] = o;
    } else {
        if (w < 2) obuf[w][lane] = o;           // nodes 4b (user), 4b+1 (item)
        __syncthreads();
        if (w == 0) {
            float p = obuf[0][lane] * obuf[1][lane];
            for (int off = 32; off > 0; off >>= 1) p += __shfl_down(p, off, 64);
            if (lane == 0) out[blockIdx.x] = p;
        }
    }
}

// ---------------- launch ----------------
extern "C" void kernel_launch(void* const* d_in, const int* in_sizes, int n_in,
                              void* d_out, int out_size, void* d_ws, size_t ws_size,
                              hipStream_t stream) {
    const float* x       = (const float*)d_in[0];   // [N,4]
    const float* W0      = (const float*)d_in[1];   // [4,64]
    const float* W13     = (const float*)d_in[2];   // [3,64,64]
    const float* eemb    = (const float*)d_in[3];   // [4,5,64]
    const float* att_src = (const float*)d_in[4];   // [4,2,32]
    const float* att_dst = (const float*)d_in[5];   // [4,2,32]
    const float* bias    = (const float*)d_in[6];   // [4,64]
    const int*   eidx    = (const int*)d_in[7];     // [2,E]
    const int*   eattr   = (const int*)d_in[8];     // [E]
    float* out = (float*)d_out;

    const int* src = eidx;
    const int* dst = eidx + N_EDGES;

    // workspace layout
    char* wsb = (char*)d_ws;
    size_t off = 0;
    auto alloc = [&](size_t bytes) { char* p = wsb + off; off += (bytes + 255) & ~(size_t)255; return p; };
    float*          hprev    = (float*)alloc((size_t)N_NODES * HC * 4);
    unsigned short* hcurb    = (unsigned short*)alloc((size_t)N_NODES * HC * 2);
    float*          ssrc     = (float*)alloc((size_t)N_NODES * 2 * 4);
    float*          sdst     = (float*)alloc((size_t)N_NODES * 2 * 4);
    float*          escore   = (float*)alloc(NLAYERS * ECLS * NHEADS * 4);
    int*            bh       = (int*)alloc((size_t)NBUCK * 256 * 4);
    int*            bbase    = (int*)alloc((size_t)NBUCK * 256 * 4);
    int*            part     = (int*)alloc(256 * 4);
    int*            rowstart = (int*)alloc(((size_t)N_NODES + 1) * 4);
    int*            bkt      = (int*)alloc((size_t)N_EDGES * 4);
    int*            packed   = (int*)alloc((size_t)N_EDGES * 4);

    const int nodeBlocks = N_NODES / 4;              // 25000, exact
    const int linBlocks  = 2048;                     // grid-stride waves

    // ---- CSR build: bucket sort, no global atomics ----
    k_chist<<<NBLK, 256, 0, stream>>>(dst, bh);
    k_s1<<<NBUCK, 256, 0, stream>>>(bh, bbase, part);
    k_s2<<<1, 256, 0, stream>>>(part, eemb, att_src, escore);
    k_cscatter<<<NBLK, 256, 0, stream>>>(src, dst, eattr, bbase, part, bkt);
    k_fine<<<NBUCK, 512, 0, stream>>>(part, bkt, packed, rowstart);

    for (int l = 0; l < NLAYERS; ++l) {
        const float* asr = att_src + l * HC;
        const float* ads = att_dst + l * HC;
        const float* el  = eemb + (size_t)l * ECLS * HC;
        const float* esl = escore + l * ECLS * NHEADS;
        const float* bl  = bias + l * HC;

        if (l == 0)
            k_linear<4><<<linBlocks, 256, 0, stream>>>(x, W0, asr, ads, hcurb, ssrc, sdst);
        else
            k_linear<64><<<linBlocks, 256, 0, stream>>>(hprev, W13 + (size_t)(l - 1) * HC * HC,
                                                        asr, ads, hcurb, ssrc, sdst);
        if (l < NLAYERS - 1)
            k_edge<false><<<nodeBlocks, 256, 0, stream>>>(rowstart, packed, ssrc, sdst, esl,
                                                          hcurb, el, bl, hprev, nullptr);
        else
            k_edge<true><<<nodeBlocks, 256, 0, stream>>>(rowstart, packed, ssrc, sdst, esl,
                                                         hcurb, el, bl, hprev, out);
    }
}

// Round 10
// 425.390 us; speedup vs baseline: 6.9517x; 1.0225x over previous
//
#include <hip/hip_runtime.h>
#include <hip/hip_bf16.h>
#include <math.h>

#define N_NODES 100000
#define N_EDGES 1600000
#define HC 64          // H*C
#define NHEADS 2
#define NLAYERS 4
#define ECLS 5
#define NBUCK 196              // ceil(N / 512); bucket = dst >> 9
#define NBLK 256               // coarse pass blocks
#define EPB (N_EDGES / NBLK)   // 6250 edges per coarse block (exact)

// bf16 (stored as ushort) -> f32
__device__ inline float bf_lo(unsigned int u) { return __uint_as_float(u << 16); }
__device__ inline float bf_hi(unsigned int u) { return __uint_as_float(u & 0xffff0000u); }
// f32 -> bf16 bits, round-to-nearest-even
__device__ inline unsigned short f2bf(float f) {
    unsigned int u = __float_as_uint(f);
    u += 0x7FFFu + ((u >> 16) & 1u);
    return (unsigned short)(u >> 16);
}

// ---------------- CSR build: two-level bucket sort, no global atomics ------

// P1: per-(bucket,block) counts. Block b handles edges [b*EPB, (b+1)*EPB).
__global__ void k_chist(const int* __restrict__ dst, int* __restrict__ bh) {
    __shared__ int lh[NBUCK];
    int tid = threadIdx.x, blk = blockIdx.x;
    for (int i = tid; i < NBUCK; i += 256) lh[i] = 0;
    __syncthreads();
    int s = blk * EPB, e = s + EPB;
    for (int i = s + tid; i < e; i += 256) atomicAdd(&lh[dst[i] >> 9], 1);
    __syncthreads();
    for (int i = tid; i < NBUCK; i += 256) bh[i * 256 + blk] = lh[i];
}

// P2a: per-bucket (256-tile) exclusive scan of bh -> bbase, bucket sums -> part.
__global__ void k_s1(const int* __restrict__ bh, int* __restrict__ bbase,
                     int* __restrict__ part) {
    __shared__ int tmp[256];
    int tid = threadIdx.x;
    int i = blockIdx.x * 256 + tid;
    int v = bh[i];
    tmp[tid] = v;
    __syncthreads();
    for (int off = 1; off < 256; off <<= 1) {
        int t = (tid >= off) ? tmp[tid - off] : 0;
        __syncthreads();
        tmp[tid] += t;
        __syncthreads();
    }
    bbase[i] = tmp[tid] - v;
    if (tid == 255) part[blockIdx.x] = tmp[255];
}

// P2b: exclusive scan of the NBUCK bucket sums in-place (part becomes bucket base).
// Also computes escore[l][c][h] (folded in to save a launch).
__global__ void k_s2(int* __restrict__ part,
                     const float* __restrict__ eemb, const float* __restrict__ att_src,
                     float* __restrict__ escore) {
    __shared__ int tmp[256];
    int tid = threadIdx.x;
    int v = (tid < NBUCK) ? part[tid] : 0;
    tmp[tid] = v;
    __syncthreads();
    for (int off = 1; off < 256; off <<= 1) {
        int t = (tid >= off) ? tmp[tid - off] : 0;
        __syncthreads();
        tmp[tid] += t;
        __syncthreads();
    }
    if (tid < NBUCK) part[tid] = tmp[tid] - v;
    if (tid >= 200 && tid < 200 + NLAYERS * ECLS * NHEADS) {
        int idx = tid - 200;
        int l = idx / (ECLS * NHEADS);
        int r = idx % (ECLS * NHEADS);
        int c = r >> 1;
        int h = r & 1;
        float s = 0.f;
        const float* ev = eemb + l * ECLS * HC + c * HC + h * 32;
        const float* av = att_src + l * HC + h * 32;
        for (int k = 0; k < 32; ++k) s += ev[k] * av[k];
        escore[idx] = s;
    }
}

// P3: coarse scatter into bucket-grouped array; LDS atomics only.
// Global base = bbase[bucket*256+blk] (within-bucket) + part[bucket] (bucket base).
__global__ void k_cscatter(const int* __restrict__ src, const int* __restrict__ dst,
                           const int* __restrict__ attr, const int* __restrict__ bbase,
                           const int* __restrict__ part, int* __restrict__ bkt) {
    __shared__ int cur[NBUCK];
    int tid = threadIdx.x, blk = blockIdx.x;
    for (int i = tid; i < NBUCK; i += 256) cur[i] = bbase[i * 256 + blk] + part[i];
    __syncthreads();
    int s0 = blk * EPB, e0 = s0 + EPB;
    for (int i = s0 + tid; i < e0; i += 256) {
        int d = dst[i];
        int b = d >> 9;
        int pos = atomicAdd(&cur[b], 1);
        bkt[pos] = src[i] | (attr[i] << 17) | ((d & 511) << 20);
    }
}

// P4: fine sort within each bucket (512 nodes); emits final packed + rowstart.
__global__ void k_fine(const int* __restrict__ part, const int* __restrict__ bkt,
                       int* __restrict__ packed, int* __restrict__ rowstart) {
    __shared__ int hist[512];
    __shared__ int cur[512];
    int b = blockIdx.x, tid = threadIdx.x;   // 512 threads
    int base = part[b];
    int bend = (b + 1 < NBUCK) ? part[b + 1] : N_EDGES;
    int nb = bend - base;
    hist[tid] = 0;
    __syncthreads();
    for (int i = tid; i < nb; i += 512)
        atomicAdd(&hist[(bkt[base + i] >> 20) & 0x1FF], 1);
    __syncthreads();
    int v = hist[tid];
    for (int off = 1; off < 512; off <<= 1) {
        int t = (tid >= off) ? hist[tid - off] : 0;
        __syncthreads();
        hist[tid] += t;
        __syncthreads();
    }
    int excl = hist[tid] - v;
    int node = (b << 9) + tid;
    if (node <= N_NODES) rowstart[node] = base + excl;
    cur[tid] = excl;
    __syncthreads();
    for (int i = tid; i < nb; i += 512) {
        int p = bkt[base + i];
        int r = atomicAdd(&cur[(p >> 20) & 0x1FF], 1);
        packed[base + r] = p;
    }
}

// ---------------- per-layer kernels ----------------

// hcur(bf16) = in @ W ; per-node attention partials ssrc/sdst (fp32).
// FIN=64: one wave handles groups of 4 nodes. Stage 4 rows (1 KB) in this
// wave's LDS quarter via coalesced float4 loads, then 16 ds_read_b128
// BROADCASTS (same addr all lanes = conflict-free) + 64 FMAs per node.
// W column j lives in lane j's registers. No __syncthreads, no scalar-cache chain.
// FIN=4: wave-uniform scalar row loads (input is tiny).
template <int FIN>
__global__ void k_linear(const float* __restrict__ in,
                         const float* __restrict__ W,        // [FIN][64]
                         const float* __restrict__ asrc,     // [2][32]
                         const float* __restrict__ adst,     // [2][32]
                         unsigned short* __restrict__ hcurb, // [N][64] bf16
                         float* __restrict__ ssrc, float* __restrict__ sdst) {
    __shared__ float rows[4][256];   // 4 waves x (4 rows x 64 floats)
    int tid = threadIdx.x;
    int j = tid & 63;
    int w = tid >> 6;

    float wreg[FIN];
    #pragma unroll
    for (int k = 0; k < FIN; ++k) wreg[k] = W[k * HC + j];

    int head = j >> 5;
    int c = j & 31;
    float as = asrc[head * 32 + c];
    float ad = adst[head * 32 + c];

    int wid = (blockIdx.x * 256 + tid) >> 6;
    int nwaves = gridDim.x * 4;

    if (FIN == 64) {
        for (int g = wid; g < N_NODES / 4; g += nwaves) {
            int base = g * 4;
            // stage 4 rows coalesced: lane j loads float4 #j of the 1 KB block
            ((float4*)&rows[w][0])[j] = ((const float4*)(in + (size_t)base * 64))[j];
            __builtin_amdgcn_wave_barrier();
            #pragma unroll
            for (int u = 0; u < 4; ++u) {
                int n = base + u;
                const float4* rp = (const float4*)&rows[w][u * 64];
                float acc = 0.f;
                #pragma unroll
                for (int k4 = 0; k4 < 16; ++k4) {
                    float4 r = rp[k4];           // broadcast read
                    acc += r.x * wreg[k4 * 4 + 0];
                    acc += r.y * wreg[k4 * 4 + 1];
                    acc += r.z * wreg[k4 * 4 + 2];
                    acc += r.w * wreg[k4 * 4 + 3];
                }
                hcurb[(size_t)n * HC + j] = f2bf(acc);
                float ps = acc * as;
                float pd = acc * ad;
                for (int off = 16; off > 0; off >>= 1) {
                    ps += __shfl_down(ps, off, 32);
                    pd += __shfl_down(pd, off, 32);
                }
                if (c == 0) {
                    ssrc[n * 2 + head] = ps;
                    sdst[n * 2 + head] = pd;
                }
            }
            __builtin_amdgcn_wave_barrier();     // before next stage overwrites
        }
    } else {
        for (int n = wid; n < N_NODES; n += nwaves) {
            int nu = __builtin_amdgcn_readfirstlane(n);
            const float* row = in + (size_t)nu * FIN;
            float acc = 0.f;
            #pragma unroll
            for (int k4 = 0; k4 < FIN / 4; ++k4) {
                float4 r = ((const float4*)row)[k4];
                acc += r.x * wreg[k4 * 4 + 0];
                acc += r.y * wreg[k4 * 4 + 1];
                acc += r.z * wreg[k4 * 4 + 2];
                acc += r.w * wreg[k4 * 4 + 3];
            }
            hcurb[(size_t)nu * HC + j] = f2bf(acc);
            float ps = acc * as;
            float pd = acc * ad;
            for (int off = 16; off > 0; off >>= 1) {
                ps += __shfl_down(ps, off, 32);
                pd += __shfl_down(pd, off, 32);
            }
            if (c == 0) {
                ssrc[nu * 2 + head] = ps;
                sdst[nu * 2 + head] = pd;
            }
        }
    }
}

// Fused edge pipeline: one wave per dst node; block = 4 nodes.
// Lane layout: sub = lane>>3 (edge slot 0..7), q = lane&7 (channels 8q..8q+7).
// Epilogue: LDS bounce so all 64 lanes do 1-channel ELU. The normalizer for
// channel `lane` must use head lane>>5: fetch that head's ssum via shfl from
// lane (lane>>5)*4 (q=0 holds head0 sum, q=4 holds head1 sum after reduction).
// LAST: fuse the MF decoder — out[b] = dot(h[4b], h[4b+1]); skip hnext store.
template <bool LAST>
__global__ void k_edge(const int* __restrict__ rowstart, const int* __restrict__ packed,
                       const float* __restrict__ ssrc, const float* __restrict__ sdst,
                       const float* __restrict__ escore_l,   // [5][2]
                       const unsigned short* __restrict__ hcurb, // [N][64] bf16
                       const float* __restrict__ eemb_l,     // [5][64]
                       const float* __restrict__ bias_l,     // [64]
                       float* __restrict__ hnext, float* __restrict__ out) {
    __shared__ float lbuf[4][64];
    __shared__ float obuf[2][64];
    int w = threadIdx.x >> 6;
    int n = blockIdx.x * 4 + w;                 // always < N (grid = N/4 exact)
    int lane = threadIdx.x & 63;
    int sub = lane >> 3;       // edge slot 0..7
    int q   = lane & 7;        // channel octet: channels 8q..8q+7
    int h   = q >> 2;          // head for the LOOP role (q<4 -> head0)

    int beg = rowstart[n];
    int end = rowstart[n + 1];
    float sd = sdst[n * 2 + h];

    float4 a0 = make_float4(0.f, 0.f, 0.f, 0.f);
    float4 a1 = make_float4(0.f, 0.f, 0.f, 0.f);
    float ssum = 0.f;
    for (int i = beg + sub; i < end; i += 8) {
        int p = packed[i];
        int s = p & 0x1FFFF;
        int a = (p >> 17) & 7;
        float lg = sd + ssrc[s * 2 + h] + escore_l[a * 2 + h];
        lg = lg >= 0.f ? lg : 0.2f * lg;
        float wt = __expf(lg);
        uint4 hv = *(const uint4*)(hcurb + (size_t)s * HC + q * 8);
        const float4* ep = (const float4*)(eemb_l + a * HC + q * 8);
        float4 e0 = ep[0], e1 = ep[1];
        a0.x += wt * (bf_lo(hv.x) + e0.x);
        a0.y += wt * (bf_hi(hv.x) + e0.y);
        a0.z += wt * (bf_lo(hv.y) + e0.z);
        a0.w += wt * (bf_hi(hv.y) + e0.w);
        a1.x += wt * (bf_lo(hv.z) + e1.x);
        a1.y += wt * (bf_hi(hv.z) + e1.y);
        a1.z += wt * (bf_lo(hv.w) + e1.z);
        a1.w += wt * (bf_hi(hv.w) + e1.w);
        ssum += wt;
    }
    // reduce the 8 edge slots (lanes differing in bits 3,4,5; q/head preserved)
    for (int off = 8; off < 64; off <<= 1) {
        a0.x += __shfl_xor(a0.x, off, 64);
        a0.y += __shfl_xor(a0.y, off, 64);
        a0.z += __shfl_xor(a0.z, off, 64);
        a0.w += __shfl_xor(a0.w, off, 64);
        a1.x += __shfl_xor(a1.x, off, 64);
        a1.y += __shfl_xor(a1.y, off, 64);
        a1.z += __shfl_xor(a1.z, off, 64);
        a1.w += __shfl_xor(a1.w, off, 64);
        ssum  += __shfl_xor(ssum,  off, 64);
    }
    if (sub == 0) {
        ((float4*)&lbuf[w][q * 8])[0] = a0;
        ((float4*)&lbuf[w][q * 8])[1] = a1;
    }
    // ssum for the head of CHANNEL `lane` (= lane>>5): lane 0 holds head0 sum,
    // lane 4 holds head1 sum (replicated over sub after the reduction).
    float ssum_h = __shfl(ssum, (lane >> 5) * 4, 64);
    float inv = 1.f / (ssum_h + 1e-16f);
    __builtin_amdgcn_wave_barrier();            // DS ops are in-order per wave
    float v = lbuf[w][lane] * inv + bias_l[lane];
    float o = v > 0.f ? v : (__expf(v) - 1.f);  // elu; expf-1 ~= expm1 well within tol
    if (!LAST) {
        hnext[(size_t)n * HC + lane] = o;
    } else {
        if (w < 2) obuf[w][lane] = o;           // nodes 4b (user), 4b+1 (item)
        __syncthreads();
        if (w == 0) {
            float p = obuf[0][lane] * obuf[1][lane];
            for (int off = 32; off > 0; off >>= 1) p += __shfl_down(p, off, 64);
            if (lane == 0) out[blockIdx.x] = p;
        }
    }
}

// ---------------- launch ----------------
extern "C" void kernel_launch(void* const* d_in, const int* in_sizes, int n_in,
                              void* d_out, int out_size, void* d_ws, size_t ws_size,
                              hipStream_t stream) {
    const float* x       = (const float*)d_in[0];   // [N,4]
    const float* W0      = (const float*)d_in[1];   // [4,64]
    const float* W13     = (const float*)d_in[2];   // [3,64,64]
    const float* eemb    = (const float*)d_in[3];   // [4,5,64]
    const float* att_src = (const float*)d_in[4];   // [4,2,32]
    const float* att_dst = (const float*)d_in[5];   // [4,2,32]
    const float* bias    = (const float*)d_in[6];   // [4,64]
    const int*   eidx    = (const int*)d_in[7];     // [2,E]
    const int*   eattr   = (const int*)d_in[8];     // [E]
    float* out = (float*)d_out;

    const int* src = eidx;
    const int* dst = eidx + N_EDGES;

    // workspace layout
    char* wsb = (char*)d_ws;
    size_t off = 0;
    auto alloc = [&](size_t bytes) { char* p = wsb + off; off += (bytes + 255) & ~(size_t)255; return p; };
    float*          hprev    = (float*)alloc((size_t)N_NODES * HC * 4);
    unsigned short* hcurb    = (unsigned short*)alloc((size_t)N_NODES * HC * 2);
    float*          ssrc     = (float*)alloc((size_t)N_NODES * 2 * 4);
    float*          sdst     = (float*)alloc((size_t)N_NODES * 2 * 4);
    float*          escore   = (float*)alloc(NLAYERS * ECLS * NHEADS * 4);
    int*            bh       = (int*)alloc((size_t)NBUCK * 256 * 4);
    int*            bbase    = (int*)alloc((size_t)NBUCK * 256 * 4);
    int*            part     = (int*)alloc(256 * 4);
    int*            rowstart = (int*)alloc(((size_t)N_NODES + 1) * 4);
    int*            bkt      = (int*)alloc((size_t)N_EDGES * 4);
    int*            packed   = (int*)alloc((size_t)N_EDGES * 4);

    const int nodeBlocks = N_NODES / 4;              // 25000, exact
    const int linBlocks  = 1024;                     // grid-stride waves

    // ---- CSR build: bucket sort, no global atomics ----
    k_chist<<<NBLK, 256, 0, stream>>>(dst, bh);
    k_s1<<<NBUCK, 256, 0, stream>>>(bh, bbase, part);
    k_s2<<<1, 256, 0, stream>>>(part, eemb, att_src, escore);
    k_cscatter<<<NBLK, 256, 0, stream>>>(src, dst, eattr, bbase, part, bkt);
    k_fine<<<NBUCK, 512, 0, stream>>>(part, bkt, packed, rowstart);

    for (int l = 0; l < NLAYERS; ++l) {
        const float* asr = att_src + l * HC;
        const float* ads = att_dst + l * HC;
        const float* el  = eemb + (size_t)l * ECLS * HC;
        const float* esl = escore + l * ECLS * NHEADS;
        const float* bl  = bias + l * HC;

        if (l == 0)
            k_linear<4><<<linBlocks, 256, 0, stream>>>(x, W0, asr, ads, hcurb, ssrc, sdst);
        else
            k_linear<64><<<linBlocks, 256, 0, stream>>>(hprev, W13 + (size_t)(l - 1) * HC * HC,
                                                        asr, ads, hcurb, ssrc, sdst);
        if (l < NLAYERS - 1)
            k_edge<false><<<nodeBlocks, 256, 0, stream>>>(rowstart, packed, ssrc, sdst, esl,
                                                          hcurb, el, bl, hprev, nullptr);
        else
            k_edge<true><<<nodeBlocks, 256, 0, stream>>>(rowstart, packed, ssrc, sdst, esl,
                                                         hcurb, el, bl, hprev, out);
    }
}